// Round 10
// baseline (363.992 us; speedup 1.0000x reference)
//
#include <hip/hip_runtime.h>
#include <math.h>

#define N_NODES 100000
#define N_EDGES 3200000
#define N_TOT   (N_EDGES + N_NODES)
#define F_IN    512
#define HID     16
#define NCLS    32
#define NEG_SLOPE 0.2f

#define BSH   7                       // bucket shift: 128 nodes per bucket
#define NBKT  ((N_NODES + 127) / 128) // 782
#define SRC_MASK 0x1FFFF              // 17 bits, N_NODES < 131072

#define G_GROUPS 512
#define EPG (N_EDGES / G_GROUPS)      // 6250 exact

// ---------- edge dtype detection (int64 vs int32) ----------
__global__ __launch_bounds__(64) void k_detect(const int* __restrict__ ei,
                                               int* __restrict__ flag) {
  int v = ei[2 * threadIdx.x + 1];
  unsigned long long m = __ballot(v != 0);
  if (threadIdx.x == 0) *flag = (m == 0ull) ? 1 : 0;  // 1 => int64 layout
}

// ---------- phase 1: per-group LDS histogram over dst buckets ----------
__global__ __launch_bounds__(256) void k_hist(const int* __restrict__ ei,
                                              const int* __restrict__ flag,
                                              int* __restrict__ H) {
  __shared__ int h[NBKT];
  for (int i = threadIdx.x; i < NBKT; i += 256) h[i] = 0;
  __syncthreads();
  int fl = *flag;
  int g = blockIdx.x;
  int e0 = g * EPG, e1 = e0 + EPG;
  for (int e = e0 + threadIdx.x; e < e1; e += 256) {
    int d = fl ? ei[2 * (N_EDGES + e)] : ei[N_EDGES + e];
    d = min(max(d, 0), N_NODES - 1);
    atomicAdd(&h[d >> BSH], 1);
  }
  __syncthreads();
  int* Hrow = H + (size_t)g * NBKT;
  for (int i = threadIdx.x; i < NBKT; i += 256) Hrow[i] = h[i];
}

// ---------- phase 2a: per-bucket exclusive scan over groups ----------
__global__ __launch_bounds__(G_GROUPS) void k_colscan(int* __restrict__ H,
                                                      int* __restrict__ tot) {
  __shared__ int s[G_GROUPS];
  int b = blockIdx.x, t = threadIdx.x;
  int v = H[(size_t)t * NBKT + b];
  s[t] = v;
  __syncthreads();
  for (int off = 1; off < G_GROUPS; off <<= 1) {
    int a = (t >= off) ? s[t - off] : 0;
    __syncthreads();
    s[t] += a;
    __syncthreads();
  }
  H[(size_t)t * NBKT + b] = s[t] - v;     // exclusive prefix within bucket
  if (t == G_GROUPS - 1) tot[b] = s[t];   // bucket total
}

// ---------- phase 2b: scan bucket totals ----------
__global__ __launch_bounds__(256) void k_bscan(const int* __restrict__ tot,
                                               int* __restrict__ bbase,
                                               int* __restrict__ cbase,
                                               int* __restrict__ offs) {
  __shared__ int s1[256], s2[256];
  int t = threadIdx.x;
  int c[4], vn[4];
  int sum1 = 0, sum2 = 0;
#pragma unroll
  for (int j = 0; j < 4; ++j) {
    int idx = t * 4 + j;
    int cc = 0, vv = 0;
    if (idx < NBKT) {
      cc = tot[idx];
      int lo = idx << BSH;
      vv = min(128, N_NODES - lo);
    }
    c[j] = cc; vn[j] = vv;
    sum1 += cc; sum2 += cc + vv;
  }
  int o1 = sum1, o2 = sum2;
  s1[t] = sum1; s2[t] = sum2;
  __syncthreads();
  for (int off = 1; off < 256; off <<= 1) {
    int a = 0, b = 0;
    if (t >= off) { a = s1[t - off]; b = s2[t - off]; }
    __syncthreads();
    s1[t] += a; s2[t] += b;
    __syncthreads();
  }
  int r1 = s1[t] - o1;
  int r2 = s2[t] - o2;
#pragma unroll
  for (int j = 0; j < 4; ++j) {
    int idx = t * 4 + j;
    if (idx < NBKT) {
      bbase[idx] = r1; cbase[idx] = r2;
      r1 += c[j];
      r2 += c[j] + vn[j];
    }
  }
  if (t == 0) offs[N_NODES] = N_TOT;
}

// ---------- phase 3: rank-scatter into bucket bins (LDS cursors only) ----------
__global__ __launch_bounds__(256) void k_scatter(const int* __restrict__ ei,
                                                 const int* __restrict__ flag,
                                                 const int* __restrict__ H,
                                                 const int* __restrict__ bbase,
                                                 int* __restrict__ binned) {
  __shared__ int cur[NBKT];
  int g = blockIdx.x, t = threadIdx.x;
  const int* Hrow = H + (size_t)g * NBKT;
  for (int i = t; i < NBKT; i += 256) cur[i] = bbase[i] + Hrow[i];
  __syncthreads();
  int fl = *flag;
  int e0 = g * EPG, e1 = e0 + EPG;
  for (int e = e0 + t; e < e1; e += 256) {
    int s, d;
    if (fl) { s = ei[2 * e]; d = ei[2 * (N_EDGES + e)]; }
    else    { s = ei[e];     d = ei[N_EDGES + e]; }
    s = min(max(s, 0), N_NODES - 1);
    d = min(max(d, 0), N_NODES - 1);
    int p = atomicAdd(&cur[d >> BSH], 1);
    p = min(max(p, 0), N_EDGES - 1);
    binned[p] = ((d & 127) << 17) | s;
  }
}

// ---------- per-bucket counting sort in LDS -> CSR offs + srcS ----------
__global__ __launch_bounds__(256) void k_bucket(const int* __restrict__ tot,
                                                const int* __restrict__ bbase,
                                                const int* __restrict__ cbase,
                                                const int* __restrict__ binned,
                                                int* __restrict__ offs,
                                                int* __restrict__ srcS) {
  __shared__ int cnt[128], cur[128], sc[128];
  __shared__ int hdr[3];
  int b = blockIdx.x, t = threadIdx.x;
  if (t == 0) {
    hdr[0] = min(max(tot[b], 0), N_EDGES);
    hdr[1] = min(max(bbase[b], 0), N_EDGES - 1);
    hdr[2] = min(max(cbase[b], 0), N_TOT - 1);
  }
  if (t < 128) cnt[t] = 0;
  __syncthreads();
  int nb = hdr[0], base = hdr[1], cb = hdr[2];

  for (int i = t; i < nb; i += 256) {
    int pk = binned[min(base + i, N_EDGES - 1)];
    atomicAdd(&cnt[(pk >> 17) & 127], 1);
  }
  __syncthreads();

  int node = (b << BSH) + t;
  int myv = 0;
  if (t < 128) myv = (node < N_NODES) ? cnt[t] + 1 : 0;  // +1 self loop
  if (t < 128) sc[t] = myv;
  __syncthreads();
  for (int off = 1; off < 128; off <<= 1) {
    int v = 0;
    if (t < 128 && t >= off) v = sc[t - off];
    __syncthreads();
    if (t < 128) sc[t] += v;
    __syncthreads();
  }
  if (t < 128 && node < N_NODES) {
    int lofs = sc[t] - myv;
    int o = min(cb + lofs, N_TOT - 1);
    offs[node] = o;
    srcS[o] = node;                  // self-loop occupies slot 0
    cur[t] = lofs + 1;
  }
  __syncthreads();

  for (int i = t; i < nb; i += 256) {
    int pk = binned[min(base + i, N_EDGES - 1)];
    int p = atomicAdd(&cur[(pk >> 17) & 127], 1);
    srcS[min(cb + p, N_TOT - 1)] = pk & SRC_MASK;
  }
}

// ---------- tiny prep: ws2 = W2 @ att_src2, wd2 = W2 @ att_dst2 ----------
__global__ __launch_bounds__(64) void k_prep(const float* __restrict__ W2,
                                             const float* __restrict__ as2w,
                                             const float* __restrict__ ad2w,
                                             float* __restrict__ ws2,
                                             float* __restrict__ wd2) {
  int t = threadIdx.x;
  if (t < HID) {
    float s = 0.f, d = 0.f;
    for (int c = 0; c < NCLS; ++c) {
      float wv = W2[t * NCLS + c];
      s += wv * as2w[c];
      d += wv * ad2w[c];
    }
    ws2[t] = s;
    wd2[t] = d;
  }
}

// ---------- layer-1 GEMM: LDS-staged x, 8 waves, k-split by 4 ----------
// Block = 512 threads, 128 rows. Per 32-float k-chunk: coalesced stage of
// x[128][32] into LDS (16 lines/instr vs 64 for row-per-lane direct), then
// wave q (row-half q&1, k-quarter q>>1) reads 8 floats/row from LDS (row
// stride 36 floats -> odd float4 stride, b128 floor) and FMAs with W on the
// wave-uniform scalar path. Partials reduced via pacc[4][128][17].
// 782 blocks x 8 waves = 6256 waves; LDS 52KB -> 3 blocks/CU (24 waves/CU)
// vs round-9's 3 waves/CU latency collapse.
__global__ __launch_bounds__(512, 6) void k_gemm1(const float* __restrict__ x,
                                                  const float* __restrict__ W,
                                                  const float* __restrict__ atts,
                                                  const float* __restrict__ attd,
                                                  float* __restrict__ h,
                                                  float* __restrict__ as_,
                                                  float* __restrict__ ad_) {
  __shared__ float xs[128][36];        // 32 floats + 4 pad (9-float4 stride)
  __shared__ float pacc[4][128][17];   // [k-quarter][row][feat(+pad)]
  int t = threadIdx.x;
  int wid = t >> 6;
  int lane = t & 63;
  int rhalf = wid & 1;
  int kq = wid >> 1;                   // k-quarter, wave-uniform
  int row = rhalf * 64 + lane;
  int r0 = blockIdx.x * 128;

  float acc[HID];
#pragma unroll
  for (int f = 0; f < HID; ++f) acc[f] = 0.f;

  for (int c = 0; c < F_IN / 32; ++c) {
    // stage x[128 rows][32 floats] — 1024 float4, 2 per thread, coalesced
#pragma unroll
    for (int i = 0; i < 2; ++i) {
      int j = t + 512 * i;
      int sr = j >> 3;
      int sk4 = j & 7;
      int gr = min(r0 + sr, N_NODES - 1);
      float4 v = *(const float4*)(x + (size_t)gr * F_IN + c * 32 + sk4 * 4);
      *(float4*)(&xs[sr][sk4 * 4]) = v;
    }
    __syncthreads();
    // compute: this wave's 8 k's of the chunk; W wave-uniform (s_load path)
    const float* Wc = W + (c * 32 + kq * 8) * HID;
    float4 xa = *(const float4*)(&xs[row][kq * 8 + 0]);
    float4 xb = *(const float4*)(&xs[row][kq * 8 + 4]);
#pragma unroll
    for (int f = 0; f < HID; ++f)
      acc[f] += xa.x * Wc[0 * HID + f] + xa.y * Wc[1 * HID + f] +
                xa.z * Wc[2 * HID + f] + xa.w * Wc[3 * HID + f];
#pragma unroll
    for (int f = 0; f < HID; ++f)
      acc[f] += xb.x * Wc[4 * HID + f] + xb.y * Wc[5 * HID + f] +
                xb.z * Wc[6 * HID + f] + xb.w * Wc[7 * HID + f];
    __syncthreads();   // xs consumed before next chunk overwrites
  }

#pragma unroll
  for (int f = 0; f < HID; ++f) pacc[kq][row][f] = acc[f];
  __syncthreads();

  // reduce over the 4 k-quarters: thread -> (row rr, feat-quad g)
  int rr = t >> 2, g = t & 3;
  float4 s;
  s.x = pacc[0][rr][g * 4 + 0] + pacc[1][rr][g * 4 + 0] +
        pacc[2][rr][g * 4 + 0] + pacc[3][rr][g * 4 + 0];
  s.y = pacc[0][rr][g * 4 + 1] + pacc[1][rr][g * 4 + 1] +
        pacc[2][rr][g * 4 + 1] + pacc[3][rr][g * 4 + 1];
  s.z = pacc[0][rr][g * 4 + 2] + pacc[1][rr][g * 4 + 2] +
        pacc[2][rr][g * 4 + 2] + pacc[3][rr][g * 4 + 2];
  s.w = pacc[0][rr][g * 4 + 3] + pacc[1][rr][g * 4 + 3] +
        pacc[2][rr][g * 4 + 3] + pacc[3][rr][g * 4 + 3];
  int orow = r0 + rr;
  if (orow < N_NODES) ((float4*)(h + (size_t)orow * HID))[g] = s;

  // fused as/ad: intra-quad shuffle reduce (full wave active)
  float4 av = ((const float4*)atts)[g];
  float4 dv = ((const float4*)attd)[g];
  float pas = s.x * av.x + s.y * av.y + s.z * av.z + s.w * av.w;
  float pad = s.x * dv.x + s.y * dv.y + s.z * dv.z + s.w * dv.w;
  pas += __shfl_xor(pas, 1); pas += __shfl_xor(pas, 2);
  pad += __shfl_xor(pad, 1); pad += __shfl_xor(pad, 2);
  if (g == 0 && orow < N_NODES) { as_[orow] = pas; ad_[orow] = pad; }
}

// ---------- fused aggregate: single-sweep softmax+gather, float4 lanes ----
// Wave per node. All shuffles full-wave (clamped source, predicated use).
template <bool LAYER1>
__global__ __launch_bounds__(256) void k_agg(const int* __restrict__ offs,
                                             const int* __restrict__ srcS,
                                             const float* __restrict__ as_,
                                             const float* __restrict__ ad_,
                                             const float* __restrict__ h,
                                             const float* __restrict__ b1,
                                             const float* __restrict__ ws2,
                                             const float* __restrict__ wd2,
                                             float* __restrict__ outv,
                                             float* __restrict__ as2,
                                             float* __restrict__ ad2) {
  int node = blockIdx.x * 4 + (threadIdx.x >> 6);
  if (node >= N_NODES) return;
  int lane = threadIdx.x & 63;
  int esub = lane >> 2;     // 16 edge slots per step
  int f4 = lane & 3;        // feature quad
  int beg = offs[node];
  int end = offs[node + 1];
  beg = min(max(beg, 0), N_TOT);
  end = min(max(end, beg), N_TOT);
  float ad = ad_[node];

  float s_lane = 0.f;
  float4 acc = make_float4(0.f, 0.f, 0.f, 0.f);
  for (int i0 = beg; i0 < end; i0 += 64) {
    int nb = min(64, end - i0);
    int sn = 0;
    float p = 0.f;
    if (lane < nb) {
      sn = min(max(srcS[i0 + lane], 0), N_NODES - 1);
      float e = as_[sn] + ad;
      e = e > 0.f ? e : NEG_SLOPE * e;
      p = __expf(e);           // no max-shift: |e| <= ~12, exp safe in fp32
    }
    s_lane += p;
    int steps = (nb + 15) >> 4;
    for (int t = 0; t < steps; ++t) {
      int j = esub + 16 * t;
      int jj = min(j, nb - 1);           // clamp so source lane is valid
      float pj = __shfl(p, jj);          // full wave active
      int snj = __shfl(sn, jj);
      if (j < nb) {
        float4 v = ((const float4*)(h + (size_t)snj * HID))[f4];
        acc.x += pj * v.x;
        acc.y += pj * v.y;
        acc.z += pj * v.z;
        acc.w += pj * v.w;
      }
    }
  }
#pragma unroll
  for (int off = 1; off < 64; off <<= 1) s_lane += __shfl_xor(s_lane, off);
#pragma unroll
  for (int off = 4; off < 64; off <<= 1) {
    acc.x += __shfl_xor(acc.x, off);
    acc.y += __shfl_xor(acc.y, off);
    acc.z += __shfl_xor(acc.z, off);
    acc.w += __shfl_xor(acc.w, off);
  }
  float inv_s = 1.f / s_lane;

  if (LAYER1) {
    float4 bv = ((const float4*)b1)[f4];
    float4 val;
    val.x = fmaxf(acc.x * inv_s + bv.x, 0.f);
    val.y = fmaxf(acc.y * inv_s + bv.y, 0.f);
    val.z = fmaxf(acc.z * inv_s + bv.z, 0.f);
    val.w = fmaxf(acc.w * inv_s + bv.w, 0.f);
    if (lane < 4) ((float4*)(outv + (size_t)node * HID))[lane] = val;
    float4 w_s = ((const float4*)ws2)[f4];
    float4 w_d = ((const float4*)wd2)[f4];
    float rs = val.x * w_s.x + val.y * w_s.y + val.z * w_s.z + val.w * w_s.w;
    float rd = val.x * w_d.x + val.y * w_d.y + val.z * w_d.z + val.w * w_d.w;
    rs += __shfl_xor(rs, 1); rs += __shfl_xor(rs, 2);
    rd += __shfl_xor(rd, 1); rd += __shfl_xor(rd, 2);
    if (lane == 0) { as2[node] = rs; ad2[node] = rd; }
  } else {
    float4 val;
    val.x = acc.x * inv_s;
    val.y = acc.y * inv_s;
    val.z = acc.z * inv_s;
    val.w = acc.w * inv_s;
    if (lane < 4) ((float4*)(outv + (size_t)node * HID))[lane] = val;
  }
}

// ---------- final: out = log_softmax(agg2 @ W2 + b2), thread-per-node ----------
__global__ __launch_bounds__(256) void k_out(const float* __restrict__ agg2,
                                             const float* __restrict__ W2,
                                             const float* __restrict__ b2,
                                             float* __restrict__ out) {
  int row = blockIdx.x * 256 + threadIdx.x;
  if (row >= N_NODES) return;
  float hv[HID];
  const float4* hp = (const float4*)(agg2 + (size_t)row * HID);
#pragma unroll
  for (int j = 0; j < 4; ++j) {
    float4 v = hp[j];
    hv[4 * j] = v.x; hv[4 * j + 1] = v.y; hv[4 * j + 2] = v.z; hv[4 * j + 3] = v.w;
  }
  float acc[NCLS];
#pragma unroll
  for (int c = 0; c < NCLS; ++c) acc[c] = b2[c];
#pragma unroll
  for (int k = 0; k < HID; ++k) {
    float xv = hv[k];
    const float* Wr = W2 + k * NCLS;
#pragma unroll
    for (int c = 0; c < NCLS; ++c) acc[c] += xv * Wr[c];
  }
  float mx = -1e30f;
#pragma unroll
  for (int c = 0; c < NCLS; ++c) mx = fmaxf(mx, acc[c]);
  float se = 0.f;
#pragma unroll
  for (int c = 0; c < NCLS; ++c) se += __expf(acc[c] - mx);
  float lse = mx + __logf(se);
  float4* op = (float4*)(out + (size_t)row * NCLS);
#pragma unroll
  for (int j = 0; j < 8; ++j)
    op[j] = make_float4(acc[4 * j] - lse, acc[4 * j + 1] - lse,
                        acc[4 * j + 2] - lse, acc[4 * j + 3] - lse);
}

extern "C" void kernel_launch(void* const* d_in, const int* in_sizes, int n_in,
                              void* d_out, int out_size, void* d_ws, size_t ws_size,
                              hipStream_t stream) {
  const float* x    = (const float*)d_in[0];
  const int*   ei   = (const int*)d_in[1];
  const float* W1   = (const float*)d_in[2];
  const float* as1w = (const float*)d_in[3];
  const float* ad1w = (const float*)d_in[4];
  const float* b1   = (const float*)d_in[5];
  const float* W2   = (const float*)d_in[6];
  const float* as2w = (const float*)d_in[7];
  const float* ad2w = (const float*)d_in[8];
  const float* b2   = (const float*)d_in[9];
  float* out = (float*)d_out;

  char* w = (char*)d_ws;
  size_t off = 0;
  auto alloc = [&](size_t bytes) -> char* {
    char* p = w + off;
    off += (bytes + 511) & ~(size_t)511;
    return p;
  };
  int*   flag  = (int*)alloc(4);
  int*   tot   = (int*)alloc((size_t)NBKT * 4);
  int*   bbase = (int*)alloc((size_t)NBKT * 4);
  int*   cbase = (int*)alloc((size_t)NBKT * 4);
  int*   offs  = (int*)alloc((size_t)(N_NODES + 1) * 4);
  int*   srcS  = (int*)alloc((size_t)N_TOT * 4);
  float* ws2   = (float*)alloc((size_t)HID * 4);
  float* wd2   = (float*)alloc((size_t)HID * 4);

  // union region: {binned 12.8MB + H 1.6MB} (CSR build) vs layer arrays.
  // binned/H are dead before k_gemm1 writes h1 (stream-ordered).
  size_t region_begin = off;
  int* binned = (int*)alloc((size_t)N_EDGES * 4);
  int* H      = (int*)alloc((size_t)G_GROUPS * NBKT * 4);
  off = region_begin;
  float* h1   = (float*)alloc((size_t)N_NODES * HID * 4);
  float* as1  = (float*)alloc((size_t)N_NODES * 4);
  float* ad1  = (float*)alloc((size_t)N_NODES * 4);
  float* hr   = (float*)alloc((size_t)N_NODES * HID * 4);
  float* agg2 = (float*)alloc((size_t)N_NODES * HID * 4);
  float* as2  = (float*)alloc((size_t)N_NODES * 4);
  float* ad2  = (float*)alloc((size_t)N_NODES * 4);

  k_detect<<<1, 64, 0, stream>>>(ei, flag);
  k_hist<<<G_GROUPS, 256, 0, stream>>>(ei, flag, H);
  k_colscan<<<NBKT, G_GROUPS, 0, stream>>>(H, tot);
  k_bscan<<<1, 256, 0, stream>>>(tot, bbase, cbase, offs);
  k_scatter<<<G_GROUPS, 256, 0, stream>>>(ei, flag, H, bbase, binned);
  k_bucket<<<NBKT, 256, 0, stream>>>(tot, bbase, cbase, binned, offs, srcS);
  k_gemm1<<<(N_NODES + 127) / 128, 512, 0, stream>>>(x, W1, as1w, ad1w, h1, as1, ad1);
  k_prep<<<1, 64, 0, stream>>>(W2, as2w, ad2w, ws2, wd2);
  k_agg<true><<<(N_NODES + 3) / 4, 256, 0, stream>>>(offs, srcS, as1, ad1, h1,
                                                     b1, ws2, wd2, hr, as2, ad2);
  k_agg<false><<<(N_NODES + 3) / 4, 256, 0, stream>>>(offs, srcS, as2, ad2, hr,
                                                      nullptr, nullptr, nullptr,
                                                      agg2, nullptr, nullptr);
  k_out<<<(N_NODES + 255) / 256, 256, 0, stream>>>(agg2, W2, b2, out);
}

// Round 11
// 276.469 us; speedup vs baseline: 1.3166x; 1.3166x over previous
//
#include <hip/hip_runtime.h>
#include <math.h>

#define N_NODES 100000
#define N_EDGES 3200000
#define N_TOT   (N_EDGES + N_NODES)
#define F_IN    512
#define HID     16
#define NCLS    32
#define NEG_SLOPE 0.2f

#define BSH   7                       // bucket shift: 128 nodes per bucket
#define NBKT  ((N_NODES + 127) / 128) // 782
#define SRC_MASK 0x1FFFF              // 17 bits, N_NODES < 131072

#define G_GROUPS 512
#define EPG (N_EDGES / G_GROUPS)      // 6250 exact

// ---------- edge dtype detection (int64 vs int32) ----------
__global__ __launch_bounds__(64) void k_detect(const int* __restrict__ ei,
                                               int* __restrict__ flag) {
  int v = ei[2 * threadIdx.x + 1];
  unsigned long long m = __ballot(v != 0);
  if (threadIdx.x == 0) *flag = (m == 0ull) ? 1 : 0;  // 1 => int64 layout
}

// ---------- phase 1: per-group LDS histogram over dst buckets ----------
__global__ __launch_bounds__(256) void k_hist(const int* __restrict__ ei,
                                              const int* __restrict__ flag,
                                              int* __restrict__ H) {
  __shared__ int h[NBKT];
  for (int i = threadIdx.x; i < NBKT; i += 256) h[i] = 0;
  __syncthreads();
  int fl = *flag;
  int g = blockIdx.x;
  int e0 = g * EPG, e1 = e0 + EPG;
  for (int e = e0 + threadIdx.x; e < e1; e += 256) {
    int d = fl ? ei[2 * (N_EDGES + e)] : ei[N_EDGES + e];
    d = min(max(d, 0), N_NODES - 1);
    atomicAdd(&h[d >> BSH], 1);
  }
  __syncthreads();
  int* Hrow = H + (size_t)g * NBKT;
  for (int i = threadIdx.x; i < NBKT; i += 256) Hrow[i] = h[i];
}

// ---------- phase 2a: per-bucket exclusive scan over groups ----------
__global__ __launch_bounds__(G_GROUPS) void k_colscan(int* __restrict__ H,
                                                      int* __restrict__ tot) {
  __shared__ int s[G_GROUPS];
  int b = blockIdx.x, t = threadIdx.x;
  int v = H[(size_t)t * NBKT + b];
  s[t] = v;
  __syncthreads();
  for (int off = 1; off < G_GROUPS; off <<= 1) {
    int a = (t >= off) ? s[t - off] : 0;
    __syncthreads();
    s[t] += a;
    __syncthreads();
  }
  H[(size_t)t * NBKT + b] = s[t] - v;     // exclusive prefix within bucket
  if (t == G_GROUPS - 1) tot[b] = s[t];   // bucket total
}

// ---------- phase 2b: scan bucket totals ----------
__global__ __launch_bounds__(256) void k_bscan(const int* __restrict__ tot,
                                               int* __restrict__ bbase,
                                               int* __restrict__ cbase,
                                               int* __restrict__ offs) {
  __shared__ int s1[256], s2[256];
  int t = threadIdx.x;
  int c[4], vn[4];
  int sum1 = 0, sum2 = 0;
#pragma unroll
  for (int j = 0; j < 4; ++j) {
    int idx = t * 4 + j;
    int cc = 0, vv = 0;
    if (idx < NBKT) {
      cc = tot[idx];
      int lo = idx << BSH;
      vv = min(128, N_NODES - lo);
    }
    c[j] = cc; vn[j] = vv;
    sum1 += cc; sum2 += cc + vv;
  }
  int o1 = sum1, o2 = sum2;
  s1[t] = sum1; s2[t] = sum2;
  __syncthreads();
  for (int off = 1; off < 256; off <<= 1) {
    int a = 0, b = 0;
    if (t >= off) { a = s1[t - off]; b = s2[t - off]; }
    __syncthreads();
    s1[t] += a; s2[t] += b;
    __syncthreads();
  }
  int r1 = s1[t] - o1;
  int r2 = s2[t] - o2;
#pragma unroll
  for (int j = 0; j < 4; ++j) {
    int idx = t * 4 + j;
    if (idx < NBKT) {
      bbase[idx] = r1; cbase[idx] = r2;
      r1 += c[j];
      r2 += c[j] + vn[j];
    }
  }
  if (t == 0) offs[N_NODES] = N_TOT;
}

// ---------- phase 3: rank-scatter into bucket bins (LDS cursors only) ----------
__global__ __launch_bounds__(256) void k_scatter(const int* __restrict__ ei,
                                                 const int* __restrict__ flag,
                                                 const int* __restrict__ H,
                                                 const int* __restrict__ bbase,
                                                 int* __restrict__ binned) {
  __shared__ int cur[NBKT];
  int g = blockIdx.x, t = threadIdx.x;
  const int* Hrow = H + (size_t)g * NBKT;
  for (int i = t; i < NBKT; i += 256) cur[i] = bbase[i] + Hrow[i];
  __syncthreads();
  int fl = *flag;
  int e0 = g * EPG, e1 = e0 + EPG;
  for (int e = e0 + t; e < e1; e += 256) {
    int s, d;
    if (fl) { s = ei[2 * e]; d = ei[2 * (N_EDGES + e)]; }
    else    { s = ei[e];     d = ei[N_EDGES + e]; }
    s = min(max(s, 0), N_NODES - 1);
    d = min(max(d, 0), N_NODES - 1);
    int p = atomicAdd(&cur[d >> BSH], 1);
    p = min(max(p, 0), N_EDGES - 1);
    binned[p] = ((d & 127) << 17) | s;
  }
}

// ---------- per-bucket counting sort in LDS -> CSR offs + srcS ----------
__global__ __launch_bounds__(256) void k_bucket(const int* __restrict__ tot,
                                                const int* __restrict__ bbase,
                                                const int* __restrict__ cbase,
                                                const int* __restrict__ binned,
                                                int* __restrict__ offs,
                                                int* __restrict__ srcS) {
  __shared__ int cnt[128], cur[128], sc[128];
  __shared__ int hdr[3];
  int b = blockIdx.x, t = threadIdx.x;
  if (t == 0) {
    hdr[0] = min(max(tot[b], 0), N_EDGES);
    hdr[1] = min(max(bbase[b], 0), N_EDGES - 1);
    hdr[2] = min(max(cbase[b], 0), N_TOT - 1);
  }
  if (t < 128) cnt[t] = 0;
  __syncthreads();
  int nb = hdr[0], base = hdr[1], cb = hdr[2];

  for (int i = t; i < nb; i += 256) {
    int pk = binned[min(base + i, N_EDGES - 1)];
    atomicAdd(&cnt[(pk >> 17) & 127], 1);
  }
  __syncthreads();

  int node = (b << BSH) + t;
  int myv = 0;
  if (t < 128) myv = (node < N_NODES) ? cnt[t] + 1 : 0;  // +1 self loop
  if (t < 128) sc[t] = myv;
  __syncthreads();
  for (int off = 1; off < 128; off <<= 1) {
    int v = 0;
    if (t < 128 && t >= off) v = sc[t - off];
    __syncthreads();
    if (t < 128) sc[t] += v;
    __syncthreads();
  }
  if (t < 128 && node < N_NODES) {
    int lofs = sc[t] - myv;
    int o = min(cb + lofs, N_TOT - 1);
    offs[node] = o;
    srcS[o] = node;                  // self-loop occupies slot 0
    cur[t] = lofs + 1;
  }
  __syncthreads();

  for (int i = t; i < nb; i += 256) {
    int pk = binned[min(base + i, N_EDGES - 1)];
    int p = atomicAdd(&cur[(pk >> 17) & 127], 1);
    srcS[min(cb + p, N_TOT - 1)] = pk & SRC_MASK;
  }
}

// ---------- tiny prep: ws2 = W2 @ att_src2, wd2 = W2 @ att_dst2 ----------
__global__ __launch_bounds__(64) void k_prep(const float* __restrict__ W2,
                                             const float* __restrict__ as2w,
                                             const float* __restrict__ ad2w,
                                             float* __restrict__ ws2,
                                             float* __restrict__ wd2) {
  int t = threadIdx.x;
  if (t < HID) {
    float s = 0.f, d = 0.f;
    for (int c = 0; c < NCLS; ++c) {
      float wv = W2[t * NCLS + c];
      s += wv * as2w[c];
      d += wv * ad2w[c];
    }
    ws2[t] = s;
    wd2[t] = d;
  }
}

// ---------- layer-1 GEMM: double-buffered LDS stage + scalar-path W ----------
// Round-10 diagnosis: (a) kq derived from threadIdx.x is "divergent" to LLVM
// -> W fell off the s_load path into per-lane VMEM chains; readfirstlane
// pins kq in an SGPR so W compiles to s_load + v_fmac v,s,v (zero VMEM in
// the FMA loop). (b) single-buffered stage put global-load latency on every
// chunk's critical path; xs[2] ping-pong issues chunk c+1 loads during
// chunk c compute (one barrier/chunk). LDS ~37KB -> 4 blocks/CU.
__global__ __launch_bounds__(512) void k_gemm1(const float* __restrict__ x,
                                               const float* __restrict__ W,
                                               const float* __restrict__ atts,
                                               const float* __restrict__ attd,
                                               float* __restrict__ h,
                                               float* __restrict__ as_,
                                               float* __restrict__ ad_) {
  __shared__ float xs[2][128][36];     // 32 floats + 4 pad per row
  float* pacc = &xs[0][0][0];          // reused as [4][128][17] after compute
  int t = threadIdx.x;
  int wid = t >> 6;
  int lane = t & 63;
  int rhalf = wid & 1;
  int kq = __builtin_amdgcn_readfirstlane(wid >> 1);  // SGPR -> W on s_load path
  int row = rhalf * 64 + lane;
  int r0 = blockIdx.x * 128;

  int sr = t >> 3;                     // staging: row, float4-slot
  int sk4 = t & 7;
  int sr2 = (t + 512) >> 3;
  int sk42 = (t + 512) & 7;
  int gr1 = min(r0 + sr, N_NODES - 1);
  int gr2 = min(r0 + sr2, N_NODES - 1);

  float acc[HID];
#pragma unroll
  for (int f = 0; f < HID; ++f) acc[f] = 0.f;

  float4 ra, rb;
  // prefetch + stage chunk 0
  ra = *(const float4*)(x + (size_t)gr1 * F_IN + sk4 * 4);
  rb = *(const float4*)(x + (size_t)gr2 * F_IN + sk42 * 4);
  *(float4*)(&xs[0][sr][sk4 * 4]) = ra;
  *(float4*)(&xs[0][sr2][sk42 * 4]) = rb;
  __syncthreads();

  for (int c = 0; c < F_IN / 32; ++c) {
    int buf = c & 1;
    if (c + 1 < F_IN / 32) {           // issue next chunk's loads early
      ra = *(const float4*)(x + (size_t)gr1 * F_IN + (c + 1) * 32 + sk4 * 4);
      rb = *(const float4*)(x + (size_t)gr2 * F_IN + (c + 1) * 32 + sk42 * 4);
    }
    // compute chunk c: W wave-uniform (s_load), x from LDS
    const float* Wc = W + (c * 32 + kq * 8) * HID;
    float4 xa = *(const float4*)(&xs[buf][row][kq * 8 + 0]);
    float4 xb = *(const float4*)(&xs[buf][row][kq * 8 + 4]);
#pragma unroll
    for (int f = 0; f < HID; ++f)
      acc[f] += xa.x * Wc[0 * HID + f] + xa.y * Wc[1 * HID + f] +
                xa.z * Wc[2 * HID + f] + xa.w * Wc[3 * HID + f];
#pragma unroll
    for (int f = 0; f < HID; ++f)
      acc[f] += xb.x * Wc[4 * HID + f] + xb.y * Wc[5 * HID + f] +
                xb.z * Wc[6 * HID + f] + xb.w * Wc[7 * HID + f];
    if (c + 1 < F_IN / 32) {
      *(float4*)(&xs[buf ^ 1][sr][sk4 * 4]) = ra;    // vmcnt wait lands here
      *(float4*)(&xs[buf ^ 1][sr2][sk42 * 4]) = rb;
    }
    __syncthreads();   // chunk c reads done before xs[buf] rewritten next iter
  }

  // partial reduce across k-quarters (pacc aliases xs; compute is done)
#pragma unroll
  for (int f = 0; f < HID; ++f) pacc[(kq * 128 + row) * 17 + f] = acc[f];
  __syncthreads();

  int rr = t >> 2, g = t & 3;
  float4 s;
  s.x = pacc[(0 * 128 + rr) * 17 + g * 4 + 0] + pacc[(1 * 128 + rr) * 17 + g * 4 + 0] +
        pacc[(2 * 128 + rr) * 17 + g * 4 + 0] + pacc[(3 * 128 + rr) * 17 + g * 4 + 0];
  s.y = pacc[(0 * 128 + rr) * 17 + g * 4 + 1] + pacc[(1 * 128 + rr) * 17 + g * 4 + 1] +
        pacc[(2 * 128 + rr) * 17 + g * 4 + 1] + pacc[(3 * 128 + rr) * 17 + g * 4 + 1];
  s.z = pacc[(0 * 128 + rr) * 17 + g * 4 + 2] + pacc[(1 * 128 + rr) * 17 + g * 4 + 2] +
        pacc[(2 * 128 + rr) * 17 + g * 4 + 2] + pacc[(3 * 128 + rr) * 17 + g * 4 + 2];
  s.w = pacc[(0 * 128 + rr) * 17 + g * 4 + 3] + pacc[(1 * 128 + rr) * 17 + g * 4 + 3] +
        pacc[(2 * 128 + rr) * 17 + g * 4 + 3] + pacc[(3 * 128 + rr) * 17 + g * 4 + 3];
  int orow = r0 + rr;
  if (orow < N_NODES) ((float4*)(h + (size_t)orow * HID))[g] = s;

  // fused as/ad: intra-quad shuffle reduce (full wave active)
  float4 av = ((const float4*)atts)[g];
  float4 dv = ((const float4*)attd)[g];
  float pas = s.x * av.x + s.y * av.y + s.z * av.z + s.w * av.w;
  float pad = s.x * dv.x + s.y * dv.y + s.z * dv.z + s.w * dv.w;
  pas += __shfl_xor(pas, 1); pas += __shfl_xor(pas, 2);
  pad += __shfl_xor(pad, 1); pad += __shfl_xor(pad, 2);
  if (g == 0 && orow < N_NODES) { as_[orow] = pas; ad_[orow] = pad; }
}

// ---------- fused aggregate: single-sweep softmax+gather, float4 lanes ----
// Wave per node. All shuffles full-wave (clamped source, predicated use).
template <bool LAYER1>
__global__ __launch_bounds__(256) void k_agg(const int* __restrict__ offs,
                                             const int* __restrict__ srcS,
                                             const float* __restrict__ as_,
                                             const float* __restrict__ ad_,
                                             const float* __restrict__ h,
                                             const float* __restrict__ b1,
                                             const float* __restrict__ ws2,
                                             const float* __restrict__ wd2,
                                             float* __restrict__ outv,
                                             float* __restrict__ as2,
                                             float* __restrict__ ad2) {
  int node = blockIdx.x * 4 + (threadIdx.x >> 6);
  if (node >= N_NODES) return;
  int lane = threadIdx.x & 63;
  int esub = lane >> 2;     // 16 edge slots per step
  int f4 = lane & 3;        // feature quad
  int beg = offs[node];
  int end = offs[node + 1];
  beg = min(max(beg, 0), N_TOT);
  end = min(max(end, beg), N_TOT);
  float ad = ad_[node];

  float s_lane = 0.f;
  float4 acc = make_float4(0.f, 0.f, 0.f, 0.f);
  for (int i0 = beg; i0 < end; i0 += 64) {
    int nb = min(64, end - i0);
    int sn = 0;
    float p = 0.f;
    if (lane < nb) {
      sn = min(max(srcS[i0 + lane], 0), N_NODES - 1);
      float e = as_[sn] + ad;
      e = e > 0.f ? e : NEG_SLOPE * e;
      p = __expf(e);           // no max-shift: |e| <= ~12, exp safe in fp32
    }
    s_lane += p;
    int steps = (nb + 15) >> 4;
    for (int t = 0; t < steps; ++t) {
      int j = esub + 16 * t;
      int jj = min(j, nb - 1);           // clamp so source lane is valid
      float pj = __shfl(p, jj);          // full wave active
      int snj = __shfl(sn, jj);
      if (j < nb) {
        float4 v = ((const float4*)(h + (size_t)snj * HID))[f4];
        acc.x += pj * v.x;
        acc.y += pj * v.y;
        acc.z += pj * v.z;
        acc.w += pj * v.w;
      }
    }
  }
#pragma unroll
  for (int off = 1; off < 64; off <<= 1) s_lane += __shfl_xor(s_lane, off);
#pragma unroll
  for (int off = 4; off < 64; off <<= 1) {
    acc.x += __shfl_xor(acc.x, off);
    acc.y += __shfl_xor(acc.y, off);
    acc.z += __shfl_xor(acc.z, off);
    acc.w += __shfl_xor(acc.w, off);
  }
  float inv_s = 1.f / s_lane;

  if (LAYER1) {
    float4 bv = ((const float4*)b1)[f4];
    float4 val;
    val.x = fmaxf(acc.x * inv_s + bv.x, 0.f);
    val.y = fmaxf(acc.y * inv_s + bv.y, 0.f);
    val.z = fmaxf(acc.z * inv_s + bv.z, 0.f);
    val.w = fmaxf(acc.w * inv_s + bv.w, 0.f);
    if (lane < 4) ((float4*)(outv + (size_t)node * HID))[lane] = val;
    float4 w_s = ((const float4*)ws2)[f4];
    float4 w_d = ((const float4*)wd2)[f4];
    float rs = val.x * w_s.x + val.y * w_s.y + val.z * w_s.z + val.w * w_s.w;
    float rd = val.x * w_d.x + val.y * w_d.y + val.z * w_d.z + val.w * w_d.w;
    rs += __shfl_xor(rs, 1); rs += __shfl_xor(rs, 2);
    rd += __shfl_xor(rd, 1); rd += __shfl_xor(rd, 2);
    if (lane == 0) { as2[node] = rs; ad2[node] = rd; }
  } else {
    float4 val;
    val.x = acc.x * inv_s;
    val.y = acc.y * inv_s;
    val.z = acc.z * inv_s;
    val.w = acc.w * inv_s;
    if (lane < 4) ((float4*)(outv + (size_t)node * HID))[lane] = val;
  }
}

// ---------- final: out = log_softmax(agg2 @ W2 + b2), thread-per-node ----------
__global__ __launch_bounds__(256) void k_out(const float* __restrict__ agg2,
                                             const float* __restrict__ W2,
                                             const float* __restrict__ b2,
                                             float* __restrict__ out) {
  int row = blockIdx.x * 256 + threadIdx.x;
  if (row >= N_NODES) return;
  float hv[HID];
  const float4* hp = (const float4*)(agg2 + (size_t)row * HID);
#pragma unroll
  for (int j = 0; j < 4; ++j) {
    float4 v = hp[j];
    hv[4 * j] = v.x; hv[4 * j + 1] = v.y; hv[4 * j + 2] = v.z; hv[4 * j + 3] = v.w;
  }
  float acc[NCLS];
#pragma unroll
  for (int c = 0; c < NCLS; ++c) acc[c] = b2[c];
#pragma unroll
  for (int k = 0; k < HID; ++k) {
    float xv = hv[k];
    const float* Wr = W2 + k * NCLS;
#pragma unroll
    for (int c = 0; c < NCLS; ++c) acc[c] += xv * Wr[c];
  }
  float mx = -1e30f;
#pragma unroll
  for (int c = 0; c < NCLS; ++c) mx = fmaxf(mx, acc[c]);
  float se = 0.f;
#pragma unroll
  for (int c = 0; c < NCLS; ++c) se += __expf(acc[c] - mx);
  float lse = mx + __logf(se);
  float4* op = (float4*)(out + (size_t)row * NCLS);
#pragma unroll
  for (int j = 0; j < 8; ++j)
    op[j] = make_float4(acc[4 * j] - lse, acc[4 * j + 1] - lse,
                        acc[4 * j + 2] - lse, acc[4 * j + 3] - lse);
}

extern "C" void kernel_launch(void* const* d_in, const int* in_sizes, int n_in,
                              void* d_out, int out_size, void* d_ws, size_t ws_size,
                              hipStream_t stream) {
  const float* x    = (const float*)d_in[0];
  const int*   ei   = (const int*)d_in[1];
  const float* W1   = (const float*)d_in[2];
  const float* as1w = (const float*)d_in[3];
  const float* ad1w = (const float*)d_in[4];
  const float* b1   = (const float*)d_in[5];
  const float* W2   = (const float*)d_in[6];
  const float* as2w = (const float*)d_in[7];
  const float* ad2w = (const float*)d_in[8];
  const float* b2   = (const float*)d_in[9];
  float* out = (float*)d_out;

  char* w = (char*)d_ws;
  size_t off = 0;
  auto alloc = [&](size_t bytes) -> char* {
    char* p = w + off;
    off += (bytes + 511) & ~(size_t)511;
    return p;
  };
  int*   flag  = (int*)alloc(4);
  int*   tot   = (int*)alloc((size_t)NBKT * 4);
  int*   bbase = (int*)alloc((size_t)NBKT * 4);
  int*   cbase = (int*)alloc((size_t)NBKT * 4);
  int*   offs  = (int*)alloc((size_t)(N_NODES + 1) * 4);
  int*   srcS  = (int*)alloc((size_t)N_TOT * 4);
  float* ws2   = (float*)alloc((size_t)HID * 4);
  float* wd2   = (float*)alloc((size_t)HID * 4);

  // union region: {binned 12.8MB + H 1.6MB} (CSR build) vs layer arrays.
  // binned/H are dead before k_gemm1 writes h1 (stream-ordered).
  size_t region_begin = off;
  int* binned = (int*)alloc((size_t)N_EDGES * 4);
  int* H      = (int*)alloc((size_t)G_GROUPS * NBKT * 4);
  off = region_begin;
  float* h1   = (float*)alloc((size_t)N_NODES * HID * 4);
  float* as1  = (float*)alloc((size_t)N_NODES * 4);
  float* ad1  = (float*)alloc((size_t)N_NODES * 4);
  float* hr   = (float*)alloc((size_t)N_NODES * HID * 4);
  float* agg2 = (float*)alloc((size_t)N_NODES * HID * 4);
  float* as2  = (float*)alloc((size_t)N_NODES * 4);
  float* ad2  = (float*)alloc((size_t)N_NODES * 4);

  k_detect<<<1, 64, 0, stream>>>(ei, flag);
  k_hist<<<G_GROUPS, 256, 0, stream>>>(ei, flag, H);
  k_colscan<<<NBKT, G_GROUPS, 0, stream>>>(H, tot);
  k_bscan<<<1, 256, 0, stream>>>(tot, bbase, cbase, offs);
  k_scatter<<<G_GROUPS, 256, 0, stream>>>(ei, flag, H, bbase, binned);
  k_bucket<<<NBKT, 256, 0, stream>>>(tot, bbase, cbase, binned, offs, srcS);
  k_gemm1<<<(N_NODES + 127) / 128, 512, 0, stream>>>(x, W1, as1w, ad1w, h1, as1, ad1);
  k_prep<<<1, 64, 0, stream>>>(W2, as2w, ad2w, ws2, wd2);
  k_agg<true><<<(N_NODES + 3) / 4, 256, 0, stream>>>(offs, srcS, as1, ad1, h1,
                                                     b1, ws2, wd2, hr, as2, ad2);
  k_agg<false><<<(N_NODES + 3) / 4, 256, 0, stream>>>(offs, srcS, as2, ad2, hr,
                                                      nullptr, nullptr, nullptr,
                                                      agg2, nullptr, nullptr);
  k_out<<<(N_NODES + 255) / 256, 256, 0, stream>>>(agg2, W2, b2, out);
}

// Round 12
// 267.325 us; speedup vs baseline: 1.3616x; 1.0342x over previous
//
#include <hip/hip_runtime.h>
#include <math.h>

#define N_NODES 100000
#define N_EDGES 3200000
#define N_TOT   (N_EDGES + N_NODES)
#define F_IN    512
#define HID     16
#define NCLS    32
#define NEG_SLOPE 0.2f

#define BSH   7                       // bucket shift: 128 nodes per bucket
#define NBKT  ((N_NODES + 127) / 128) // 782
#define SRC_MASK 0x1FFFF              // 17 bits, N_NODES < 131072

#define G_GROUPS 512
#define EPG (N_EDGES / G_GROUPS)      // 6250 exact
#define NGEMM ((N_NODES + 127) / 128) // 782 gemm blocks

// ---------- edge dtype detection (int64 vs int32) ----------
__global__ __launch_bounds__(64) void k_detect(const int* __restrict__ ei,
                                               int* __restrict__ flag) {
  int v = ei[2 * threadIdx.x + 1];
  unsigned long long m = __ballot(v != 0);
  if (threadIdx.x == 0) *flag = (m == 0ull) ? 1 : 0;  // 1 => int64 layout
}

// ---------- hybrid: gemm1 (782 blocks) + hist (512) + prep (1) ----------
// Roles are independent: hist reads ei -> H; gemm reads x/W1 -> h1/as1/ad1;
// prep computes ws2/wd2. Fusing hides the latency-bound hist under the
// BW-bound gemm in one dispatch.
__global__ __launch_bounds__(512) void k_g1h(const float* __restrict__ x,
                                             const float* __restrict__ W,
                                             const float* __restrict__ atts,
                                             const float* __restrict__ attd,
                                             const int* __restrict__ ei,
                                             const int* __restrict__ flag,
                                             int* __restrict__ H,
                                             const float* __restrict__ W2,
                                             const float* __restrict__ as2w,
                                             const float* __restrict__ ad2w,
                                             float* __restrict__ ws2,
                                             float* __restrict__ wd2,
                                             float* __restrict__ h,
                                             float* __restrict__ as_,
                                             float* __restrict__ ad_) {
  __shared__ float smem[2 * 128 * 36];   // 36.9KB, reinterpreted per role
  int bid = blockIdx.x;
  int t = threadIdx.x;

  if (bid >= NGEMM) {
    if (bid < NGEMM + G_GROUPS) {
      // ---- hist role: per-group LDS histogram over dst buckets ----
      int* hh = (int*)smem;
      for (int i = t; i < NBKT; i += 512) hh[i] = 0;
      __syncthreads();
      int fl = *flag;
      int g = bid - NGEMM;
      int e0 = g * EPG, e1 = e0 + EPG;
      for (int e = e0 + t; e < e1; e += 512) {
        int d = fl ? ei[2 * (N_EDGES + e)] : ei[N_EDGES + e];
        d = min(max(d, 0), N_NODES - 1);
        atomicAdd(&hh[d >> BSH], 1);
      }
      __syncthreads();
      int* Hrow = H + (size_t)g * NBKT;
      for (int i = t; i < NBKT; i += 512) Hrow[i] = hh[i];
    } else {
      // ---- prep role: ws2 = W2 @ att_src2, wd2 = W2 @ att_dst2 ----
      if (t < HID) {
        float s = 0.f, d = 0.f;
        for (int c = 0; c < NCLS; ++c) {
          float wv = W2[t * NCLS + c];
          s += wv * as2w[c];
          d += wv * ad2w[c];
        }
        ws2[t] = s;
        wd2[t] = d;
      }
    }
    return;
  }

  // ---- gemm role (proven round-11 body): double-buffered LDS stage,
  // W on the scalar path via readfirstlane-pinned k-quarter ----
  float (*xs)[128][36] = (float (*)[128][36])smem;
  float* pacc = smem;                  // reused as [4][128][17] after compute
  int wid = t >> 6;
  int lane = t & 63;
  int rhalf = wid & 1;
  int kq = __builtin_amdgcn_readfirstlane(wid >> 1);  // SGPR -> s_load path
  int row = rhalf * 64 + lane;
  int r0 = bid * 128;

  int sr = t >> 3;
  int sk4 = t & 7;
  int sr2 = (t + 512) >> 3;
  int sk42 = (t + 512) & 7;
  int gr1 = min(r0 + sr, N_NODES - 1);
  int gr2 = min(r0 + sr2, N_NODES - 1);

  float acc[HID];
#pragma unroll
  for (int f = 0; f < HID; ++f) acc[f] = 0.f;

  float4 ra, rb;
  ra = *(const float4*)(x + (size_t)gr1 * F_IN + sk4 * 4);
  rb = *(const float4*)(x + (size_t)gr2 * F_IN + sk42 * 4);
  *(float4*)(&xs[0][sr][sk4 * 4]) = ra;
  *(float4*)(&xs[0][sr2][sk42 * 4]) = rb;
  __syncthreads();

  for (int c = 0; c < F_IN / 32; ++c) {
    int buf = c & 1;
    if (c + 1 < F_IN / 32) {
      ra = *(const float4*)(x + (size_t)gr1 * F_IN + (c + 1) * 32 + sk4 * 4);
      rb = *(const float4*)(x + (size_t)gr2 * F_IN + (c + 1) * 32 + sk42 * 4);
    }
    const float* Wc = W + (c * 32 + kq * 8) * HID;
    float4 xa = *(const float4*)(&xs[buf][row][kq * 8 + 0]);
    float4 xb = *(const float4*)(&xs[buf][row][kq * 8 + 4]);
#pragma unroll
    for (int f = 0; f < HID; ++f)
      acc[f] += xa.x * Wc[0 * HID + f] + xa.y * Wc[1 * HID + f] +
                xa.z * Wc[2 * HID + f] + xa.w * Wc[3 * HID + f];
#pragma unroll
    for (int f = 0; f < HID; ++f)
      acc[f] += xb.x * Wc[4 * HID + f] + xb.y * Wc[5 * HID + f] +
                xb.z * Wc[6 * HID + f] + xb.w * Wc[7 * HID + f];
    if (c + 1 < F_IN / 32) {
      *(float4*)(&xs[buf ^ 1][sr][sk4 * 4]) = ra;
      *(float4*)(&xs[buf ^ 1][sr2][sk42 * 4]) = rb;
    }
    __syncthreads();
  }

#pragma unroll
  for (int f = 0; f < HID; ++f) pacc[(kq * 128 + row) * 17 + f] = acc[f];
  __syncthreads();

  int rr = t >> 2, g = t & 3;
  float4 s;
  s.x = pacc[(0 * 128 + rr) * 17 + g * 4 + 0] + pacc[(1 * 128 + rr) * 17 + g * 4 + 0] +
        pacc[(2 * 128 + rr) * 17 + g * 4 + 0] + pacc[(3 * 128 + rr) * 17 + g * 4 + 0];
  s.y = pacc[(0 * 128 + rr) * 17 + g * 4 + 1] + pacc[(1 * 128 + rr) * 17 + g * 4 + 1] +
        pacc[(2 * 128 + rr) * 17 + g * 4 + 1] + pacc[(3 * 128 + rr) * 17 + g * 4 + 1];
  s.z = pacc[(0 * 128 + rr) * 17 + g * 4 + 2] + pacc[(1 * 128 + rr) * 17 + g * 4 + 2] +
        pacc[(2 * 128 + rr) * 17 + g * 4 + 2] + pacc[(3 * 128 + rr) * 17 + g * 4 + 2];
  s.w = pacc[(0 * 128 + rr) * 17 + g * 4 + 3] + pacc[(1 * 128 + rr) * 17 + g * 4 + 3] +
        pacc[(2 * 128 + rr) * 17 + g * 4 + 3] + pacc[(3 * 128 + rr) * 17 + g * 4 + 3];
  int orow = r0 + rr;
  if (orow < N_NODES) ((float4*)(h + (size_t)orow * HID))[g] = s;

  float4 av = ((const float4*)atts)[g];
  float4 dv = ((const float4*)attd)[g];
  float pas = s.x * av.x + s.y * av.y + s.z * av.z + s.w * av.w;
  float pad = s.x * dv.x + s.y * dv.y + s.z * dv.z + s.w * dv.w;
  pas += __shfl_xor(pas, 1); pas += __shfl_xor(pas, 2);
  pad += __shfl_xor(pad, 1); pad += __shfl_xor(pad, 2);
  if (g == 0 && orow < N_NODES) { as_[orow] = pas; ad_[orow] = pad; }
}

// ---------- phase 2a: per-bucket exclusive scan over groups ----------
__global__ __launch_bounds__(G_GROUPS) void k_colscan(int* __restrict__ H,
                                                      int* __restrict__ tot) {
  __shared__ int s[G_GROUPS];
  int b = blockIdx.x, t = threadIdx.x;
  int v = H[(size_t)t * NBKT + b];
  s[t] = v;
  __syncthreads();
  for (int off = 1; off < G_GROUPS; off <<= 1) {
    int a = (t >= off) ? s[t - off] : 0;
    __syncthreads();
    s[t] += a;
    __syncthreads();
  }
  H[(size_t)t * NBKT + b] = s[t] - v;     // exclusive prefix within bucket
  if (t == G_GROUPS - 1) tot[b] = s[t];   // bucket total
}

// ---------- phase 2b: scan bucket totals ----------
__global__ __launch_bounds__(256) void k_bscan(const int* __restrict__ tot,
                                               int* __restrict__ bbase,
                                               int* __restrict__ cbase,
                                               int* __restrict__ offs) {
  __shared__ int s1[256], s2[256];
  int t = threadIdx.x;
  int c[4], vn[4];
  int sum1 = 0, sum2 = 0;
#pragma unroll
  for (int j = 0; j < 4; ++j) {
    int idx = t * 4 + j;
    int cc = 0, vv = 0;
    if (idx < NBKT) {
      cc = tot[idx];
      int lo = idx << BSH;
      vv = min(128, N_NODES - lo);
    }
    c[j] = cc; vn[j] = vv;
    sum1 += cc; sum2 += cc + vv;
  }
  int o1 = sum1, o2 = sum2;
  s1[t] = sum1; s2[t] = sum2;
  __syncthreads();
  for (int off = 1; off < 256; off <<= 1) {
    int a = 0, b = 0;
    if (t >= off) { a = s1[t - off]; b = s2[t - off]; }
    __syncthreads();
    s1[t] += a; s2[t] += b;
    __syncthreads();
  }
  int r1 = s1[t] - o1;
  int r2 = s2[t] - o2;
#pragma unroll
  for (int j = 0; j < 4; ++j) {
    int idx = t * 4 + j;
    if (idx < NBKT) {
      bbase[idx] = r1; cbase[idx] = r2;
      r1 += c[j];
      r2 += c[j] + vn[j];
    }
  }
  if (t == 0) offs[N_NODES] = N_TOT;
}

// ---------- phase 3: rank-scatter into bucket bins (LDS cursors only) ----------
__global__ __launch_bounds__(256) void k_scatter(const int* __restrict__ ei,
                                                 const int* __restrict__ flag,
                                                 const int* __restrict__ H,
                                                 const int* __restrict__ bbase,
                                                 int* __restrict__ binned) {
  __shared__ int cur[NBKT];
  int g = blockIdx.x, t = threadIdx.x;
  const int* Hrow = H + (size_t)g * NBKT;
  for (int i = t; i < NBKT; i += 256) cur[i] = bbase[i] + Hrow[i];
  __syncthreads();
  int fl = *flag;
  int e0 = g * EPG, e1 = e0 + EPG;
  for (int e = e0 + t; e < e1; e += 256) {
    int s, d;
    if (fl) { s = ei[2 * e]; d = ei[2 * (N_EDGES + e)]; }
    else    { s = ei[e];     d = ei[N_EDGES + e]; }
    s = min(max(s, 0), N_NODES - 1);
    d = min(max(d, 0), N_NODES - 1);
    int p = atomicAdd(&cur[d >> BSH], 1);
    p = min(max(p, 0), N_EDGES - 1);
    binned[p] = ((d & 127) << 17) | s;
  }
}

// ---------- per-bucket counting sort in LDS -> CSR offs + srcS ----------
__global__ __launch_bounds__(256) void k_bucket(const int* __restrict__ tot,
                                                const int* __restrict__ bbase,
                                                const int* __restrict__ cbase,
                                                const int* __restrict__ binned,
                                                int* __restrict__ offs,
                                                int* __restrict__ srcS) {
  __shared__ int cnt[128], cur[128], sc[128];
  __shared__ int hdr[3];
  int b = blockIdx.x, t = threadIdx.x;
  if (t == 0) {
    hdr[0] = min(max(tot[b], 0), N_EDGES);
    hdr[1] = min(max(bbase[b], 0), N_EDGES - 1);
    hdr[2] = min(max(cbase[b], 0), N_TOT - 1);
  }
  if (t < 128) cnt[t] = 0;
  __syncthreads();
  int nb = hdr[0], base = hdr[1], cb = hdr[2];

  for (int i = t; i < nb; i += 256) {
    int pk = binned[min(base + i, N_EDGES - 1)];
    atomicAdd(&cnt[(pk >> 17) & 127], 1);
  }
  __syncthreads();

  int node = (b << BSH) + t;
  int myv = 0;
  if (t < 128) myv = (node < N_NODES) ? cnt[t] + 1 : 0;  // +1 self loop
  if (t < 128) sc[t] = myv;
  __syncthreads();
  for (int off = 1; off < 128; off <<= 1) {
    int v = 0;
    if (t < 128 && t >= off) v = sc[t - off];
    __syncthreads();
    if (t < 128) sc[t] += v;
    __syncthreads();
  }
  if (t < 128 && node < N_NODES) {
    int lofs = sc[t] - myv;
    int o = min(cb + lofs, N_TOT - 1);
    offs[node] = o;
    srcS[o] = node;                  // self-loop occupies slot 0
    cur[t] = lofs + 1;
  }
  __syncthreads();

  for (int i = t; i < nb; i += 256) {
    int pk = binned[min(base + i, N_EDGES - 1)];
    int p = atomicAdd(&cur[(pk >> 17) & 127], 1);
    srcS[min(cb + p, N_TOT - 1)] = pk & SRC_MASK;
  }
}

// ---------- fused aggregate: single-sweep softmax+gather, float4 lanes ----
// Wave per node. All shuffles full-wave (clamped source, predicated use).
// LAYER1: writes hr + fused layer-2 scores. !LAYER1: fused k_out epilogue —
// broadcast the 16-dim aggregate to all lanes, logits vs W2, log_softmax.
template <bool LAYER1>
__global__ __launch_bounds__(256) void k_agg(const int* __restrict__ offs,
                                             const int* __restrict__ srcS,
                                             const float* __restrict__ as_,
                                             const float* __restrict__ ad_,
                                             const float* __restrict__ h,
                                             const float* __restrict__ b1,
                                             const float* __restrict__ ws2,
                                             const float* __restrict__ wd2,
                                             const float* __restrict__ W2,
                                             const float* __restrict__ b2,
                                             float* __restrict__ outv,
                                             float* __restrict__ as2,
                                             float* __restrict__ ad2) {
  int node = blockIdx.x * 4 + (threadIdx.x >> 6);
  if (node >= N_NODES) return;
  int lane = threadIdx.x & 63;
  int esub = lane >> 2;     // 16 edge slots per step
  int f4 = lane & 3;        // feature quad
  int beg = offs[node];
  int end = offs[node + 1];
  beg = min(max(beg, 0), N_TOT);
  end = min(max(end, beg), N_TOT);
  float ad = ad_[node];

  float s_lane = 0.f;
  float4 acc = make_float4(0.f, 0.f, 0.f, 0.f);
  for (int i0 = beg; i0 < end; i0 += 64) {
    int nb = min(64, end - i0);
    int sn = 0;
    float p = 0.f;
    if (lane < nb) {
      sn = min(max(srcS[i0 + lane], 0), N_NODES - 1);
      float e = as_[sn] + ad;
      e = e > 0.f ? e : NEG_SLOPE * e;
      p = __expf(e);           // no max-shift: |e| <= ~12, exp safe in fp32
    }
    s_lane += p;
    int steps = (nb + 15) >> 4;
    for (int t = 0; t < steps; ++t) {
      int j = esub + 16 * t;
      int jj = min(j, nb - 1);           // clamp so source lane is valid
      float pj = __shfl(p, jj);          // full wave active
      int snj = __shfl(sn, jj);
      if (j < nb) {
        float4 v = ((const float4*)(h + (size_t)snj * HID))[f4];
        acc.x += pj * v.x;
        acc.y += pj * v.y;
        acc.z += pj * v.z;
        acc.w += pj * v.w;
      }
    }
  }
#pragma unroll
  for (int off = 1; off < 64; off <<= 1) s_lane += __shfl_xor(s_lane, off);
#pragma unroll
  for (int off = 4; off < 64; off <<= 1) {
    acc.x += __shfl_xor(acc.x, off);
    acc.y += __shfl_xor(acc.y, off);
    acc.z += __shfl_xor(acc.z, off);
    acc.w += __shfl_xor(acc.w, off);
  }
  float inv_s = 1.f / s_lane;

  if (LAYER1) {
    float4 bv = ((const float4*)b1)[f4];
    float4 val;
    val.x = fmaxf(acc.x * inv_s + bv.x, 0.f);
    val.y = fmaxf(acc.y * inv_s + bv.y, 0.f);
    val.z = fmaxf(acc.z * inv_s + bv.z, 0.f);
    val.w = fmaxf(acc.w * inv_s + bv.w, 0.f);
    if (lane < 4) ((float4*)(outv + (size_t)node * HID))[lane] = val;
    float4 w_s = ((const float4*)ws2)[f4];
    float4 w_d = ((const float4*)wd2)[f4];
    float rs = val.x * w_s.x + val.y * w_s.y + val.z * w_s.z + val.w * w_s.w;
    float rd = val.x * w_d.x + val.y * w_d.y + val.z * w_d.z + val.w * w_d.w;
    rs += __shfl_xor(rs, 1); rs += __shfl_xor(rs, 2);
    rd += __shfl_xor(rd, 1); rd += __shfl_xor(rd, 2);
    if (lane == 0) { as2[node] = rs; ad2[node] = rd; }
  } else {
    // fused k_out: every lane builds the full 16-dim aggregate via
    // full-wave shuffles (source (lane&~3)|j always valid), computes the
    // logit for class c = lane&31, then 32-lane-group log_softmax.
    float hv[HID];
#pragma unroll
    for (int j = 0; j < 4; ++j) {
      int srcl = (lane & ~3) | j;
      hv[4 * j + 0] = __shfl(acc.x, srcl) * inv_s;
      hv[4 * j + 1] = __shfl(acc.y, srcl) * inv_s;
      hv[4 * j + 2] = __shfl(acc.z, srcl) * inv_s;
      hv[4 * j + 3] = __shfl(acc.w, srcl) * inv_s;
    }
    int c = lane & 31;
    float logit = b2[c];
#pragma unroll
    for (int k = 0; k < HID; ++k) logit += hv[k] * W2[k * NCLS + c];
    float mx = logit;
#pragma unroll
    for (int off = 1; off < 32; off <<= 1) mx = fmaxf(mx, __shfl_xor(mx, off));
    float ex = __expf(logit - mx);
    float se = ex;
#pragma unroll
    for (int off = 1; off < 32; off <<= 1) se += __shfl_xor(se, off);
    if (lane < 32) outv[(size_t)node * NCLS + c] = logit - mx - __logf(se);
  }
}

extern "C" void kernel_launch(void* const* d_in, const int* in_sizes, int n_in,
                              void* d_out, int out_size, void* d_ws, size_t ws_size,
                              hipStream_t stream) {
  const float* x    = (const float*)d_in[0];
  const int*   ei   = (const int*)d_in[1];
  const float* W1   = (const float*)d_in[2];
  const float* as1w = (const float*)d_in[3];
  const float* ad1w = (const float*)d_in[4];
  const float* b1   = (const float*)d_in[5];
  const float* W2   = (const float*)d_in[6];
  const float* as2w = (const float*)d_in[7];
  const float* ad2w = (const float*)d_in[8];
  const float* b2   = (const float*)d_in[9];
  float* out = (float*)d_out;

  char* w = (char*)d_ws;
  size_t off = 0;
  auto alloc = [&](size_t bytes) -> char* {
    char* p = w + off;
    off += (bytes + 511) & ~(size_t)511;
    return p;
  };
  int*   flag  = (int*)alloc(4);
  int*   tot   = (int*)alloc((size_t)NBKT * 4);
  int*   bbase = (int*)alloc((size_t)NBKT * 4);
  int*   cbase = (int*)alloc((size_t)NBKT * 4);
  int*   offs  = (int*)alloc((size_t)(N_NODES + 1) * 4);
  int*   srcS  = (int*)alloc((size_t)N_TOT * 4);
  float* ws2   = (float*)alloc((size_t)HID * 4);
  float* wd2   = (float*)alloc((size_t)HID * 4);
  int*   H     = (int*)alloc((size_t)G_GROUPS * NBKT * 4);  // 1.6 MB
  float* h1    = (float*)alloc((size_t)N_NODES * HID * 4);
  float* as1   = (float*)alloc((size_t)N_NODES * 4);
  float* ad1   = (float*)alloc((size_t)N_NODES * 4);

  // union: binned (12.8MB, dead after k_bucket) vs {hr, as2, ad2}
  // (written by k_agg<true>, which runs after k_bucket — stream-ordered).
  size_t region_begin = off;
  int* binned = (int*)alloc((size_t)N_EDGES * 4);
  off = region_begin;
  float* hr   = (float*)alloc((size_t)N_NODES * HID * 4);
  float* as2  = (float*)alloc((size_t)N_NODES * 4);
  float* ad2  = (float*)alloc((size_t)N_NODES * 4);

  k_detect<<<1, 64, 0, stream>>>(ei, flag);
  k_g1h<<<NGEMM + G_GROUPS + 1, 512, 0, stream>>>(x, W1, as1w, ad1w, ei, flag, H,
                                                  W2, as2w, ad2w, ws2, wd2,
                                                  h1, as1, ad1);
  k_colscan<<<NBKT, G_GROUPS, 0, stream>>>(H, tot);
  k_bscan<<<1, 256, 0, stream>>>(tot, bbase, cbase, offs);
  k_scatter<<<G_GROUPS, 256, 0, stream>>>(ei, flag, H, bbase, binned);
  k_bucket<<<NBKT, 256, 0, stream>>>(tot, bbase, cbase, binned, offs, srcS);
  k_agg<true><<<(N_NODES + 3) / 4, 256, 0, stream>>>(offs, srcS, as1, ad1, h1,
                                                     b1, ws2, wd2, nullptr, nullptr,
                                                     hr, as2, ad2);
  k_agg<false><<<(N_NODES + 3) / 4, 256, 0, stream>>>(offs, srcS, as2, ad2, hr,
                                                      nullptr, nullptr, nullptr,
                                                      W2, b2, out, nullptr, nullptr);
}

// Round 13
// 257.277 us; speedup vs baseline: 1.4148x; 1.0391x over previous
//
#include <hip/hip_runtime.h>
#include <math.h>

#define N_NODES 100000
#define N_EDGES 3200000
#define N_TOT   (N_EDGES + N_NODES)
#define F_IN    512
#define HID     16
#define NCLS    32
#define NEG_SLOPE 0.2f

#define BSH   7                       // bucket shift: 128 nodes per bucket
#define NBKT  ((N_NODES + 127) / 128) // 782
#define SRC_MASK 0x1FFFF              // 17 bits, N_NODES < 131072

#define G_GROUPS 512
#define EPG (N_EDGES / G_GROUPS)      // 6250 exact (even)
#define NGEMM ((N_NODES + 127) / 128) // 782 gemm blocks

// ---------- in-block edge-dtype detection (int64 vs int32) ----------
// First wave ballots the high words of the first 64 entries; ei head is
// L2-hot after the first block. Includes a __syncthreads (doubles as the
// caller's init barrier).
__device__ __forceinline__ int detect_fl(const int* __restrict__ ei,
                                         int t, int* sflag) {
  if (t < 64) {
    int v = ei[2 * t + 1];
    unsigned long long m = __ballot(v != 0);
    if (t == 0) *sflag = (m == 0ull) ? 1 : 0;  // 1 => int64 layout
  }
  __syncthreads();
  return *sflag;
}

// ---------- hybrid: gemm1 (782 blocks) + hist (512) + prep (1) ----------
__global__ __launch_bounds__(512) void k_g1h(const float* __restrict__ x,
                                             const float* __restrict__ W,
                                             const float* __restrict__ atts,
                                             const float* __restrict__ attd,
                                             const int* __restrict__ ei,
                                             int* __restrict__ H,
                                             const float* __restrict__ W2,
                                             const float* __restrict__ as2w,
                                             const float* __restrict__ ad2w,
                                             float* __restrict__ ws2,
                                             float* __restrict__ wd2,
                                             float* __restrict__ h,
                                             float* __restrict__ as_,
                                             float* __restrict__ ad_) {
  __shared__ float smem[2 * 128 * 36];   // 36.9KB, reinterpreted per role
  int bid = blockIdx.x;
  int t = threadIdx.x;

  if (bid >= NGEMM) {
    if (bid < NGEMM + G_GROUPS) {
      // ---- hist role ----
      int* hh = (int*)smem;
      int* sflag = hh + NBKT;
      for (int i = t; i < NBKT; i += 512) hh[i] = 0;
      int fl = detect_fl(ei, t, sflag);   // barrier covers hh init
      int g = bid - NGEMM;
      int e0 = g * EPG, e1 = e0 + EPG;
      for (int e = e0 + t; e < e1; e += 512) {
        int d = fl ? ei[2 * (N_EDGES + e)] : ei[N_EDGES + e];
        d = min(max(d, 0), N_NODES - 1);
        atomicAdd(&hh[d >> BSH], 1);
      }
      __syncthreads();
      int* Hrow = H + (size_t)g * NBKT;
      for (int i = t; i < NBKT; i += 512) Hrow[i] = hh[i];
    } else {
      // ---- prep role ----
      if (t < HID) {
        float s = 0.f, d = 0.f;
        for (int c = 0; c < NCLS; ++c) {
          float wv = W2[t * NCLS + c];
          s += wv * as2w[c];
          d += wv * ad2w[c];
        }
        ws2[t] = s;
        wd2[t] = d;
      }
    }
    return;
  }

  // ---- gemm role: async-STAGE split (issue loads 2 chunks early via two
  // register sets; ds_write one full compute phase after issue) ----
  float (*xs)[128][36] = (float (*)[128][36])smem;
  float* pacc = smem;                  // reused as [4][128][17] after compute
  int wid = t >> 6;
  int lane = t & 63;
  int rhalf = wid & 1;
  int kq = __builtin_amdgcn_readfirstlane(wid >> 1);  // SGPR -> s_load path
  int row = rhalf * 64 + lane;
  int r0 = bid * 128;

  int sr = t >> 3;
  int sk4 = t & 7;
  int sr2 = (t + 512) >> 3;
  int sk42 = (t + 512) & 7;
  const float* xp1 = x + (size_t)min(r0 + sr, N_NODES - 1) * F_IN + sk4 * 4;
  const float* xp2 = x + (size_t)min(r0 + sr2, N_NODES - 1) * F_IN + sk42 * 4;

  float acc[HID];
#pragma unroll
  for (int f = 0; f < HID; ++f) acc[f] = 0.f;

  float4 a0, a1, b0, b1;
  // prologue: stage chunk 0, preload chunk 1 into rA
  a0 = *(const float4*)(xp1 + 0 * 32);
  a1 = *(const float4*)(xp2 + 0 * 32);
  *(float4*)(&xs[0][sr][sk4 * 4]) = a0;
  *(float4*)(&xs[0][sr2][sk42 * 4]) = a1;
  a0 = *(const float4*)(xp1 + 1 * 32);
  a1 = *(const float4*)(xp2 + 1 * 32);
  __syncthreads();

#pragma unroll
  for (int cc = 0; cc < 8; ++cc) {
    const int c = 2 * cc;
    // --- phase A: compute chunk c (in xs[0]), store rA (chunk c+1) ---
    if (cc < 7) {                       // load chunk c+2 -> rB (issue early)
      b0 = *(const float4*)(xp1 + (c + 2) * 32);
      b1 = *(const float4*)(xp2 + (c + 2) * 32);
    }
    {
      const float* Wc = W + (c * 32 + kq * 8) * HID;
      float4 xa = *(const float4*)(&xs[0][row][kq * 8 + 0]);
      float4 xb = *(const float4*)(&xs[0][row][kq * 8 + 4]);
#pragma unroll
      for (int f = 0; f < HID; ++f)
        acc[f] += xa.x * Wc[0 * HID + f] + xa.y * Wc[1 * HID + f] +
                  xa.z * Wc[2 * HID + f] + xa.w * Wc[3 * HID + f];
#pragma unroll
      for (int f = 0; f < HID; ++f)
        acc[f] += xb.x * Wc[4 * HID + f] + xb.y * Wc[5 * HID + f] +
                  xb.z * Wc[6 * HID + f] + xb.w * Wc[7 * HID + f];
    }
    *(float4*)(&xs[1][sr][sk4 * 4]) = a0;    // chunk c+1 (loaded 1 phase ago)
    *(float4*)(&xs[1][sr2][sk42 * 4]) = a1;
    __syncthreads();
    // --- phase B: compute chunk c+1 (in xs[1]), store rB (chunk c+2) ---
    if (cc < 7) {                       // load chunk c+3 -> rA
      a0 = *(const float4*)(xp1 + (c + 3) * 32);
      a1 = *(const float4*)(xp2 + (c + 3) * 32);
    }
    {
      const float* Wc = W + ((c + 1) * 32 + kq * 8) * HID;
      float4 xa = *(const float4*)(&xs[1][row][kq * 8 + 0]);
      float4 xb = *(const float4*)(&xs[1][row][kq * 8 + 4]);
#pragma unroll
      for (int f = 0; f < HID; ++f)
        acc[f] += xa.x * Wc[0 * HID + f] + xa.y * Wc[1 * HID + f] +
                  xa.z * Wc[2 * HID + f] + xa.w * Wc[3 * HID + f];
#pragma unroll
      for (int f = 0; f < HID; ++f)
        acc[f] += xb.x * Wc[4 * HID + f] + xb.y * Wc[5 * HID + f] +
                  xb.z * Wc[6 * HID + f] + xb.w * Wc[7 * HID + f];
    }
    if (cc < 7) {
      *(float4*)(&xs[0][sr][sk4 * 4]) = b0;  // chunk c+2
      *(float4*)(&xs[0][sr2][sk42 * 4]) = b1;
    }
    __syncthreads();
  }

#pragma unroll
  for (int f = 0; f < HID; ++f) pacc[(kq * 128 + row) * 17 + f] = acc[f];
  __syncthreads();

  int rr = t >> 2, g = t & 3;
  float4 s;
  s.x = pacc[(0 * 128 + rr) * 17 + g * 4 + 0] + pacc[(1 * 128 + rr) * 17 + g * 4 + 0] +
        pacc[(2 * 128 + rr) * 17 + g * 4 + 0] + pacc[(3 * 128 + rr) * 17 + g * 4 + 0];
  s.y = pacc[(0 * 128 + rr) * 17 + g * 4 + 1] + pacc[(1 * 128 + rr) * 17 + g * 4 + 1] +
        pacc[(2 * 128 + rr) * 17 + g * 4 + 1] + pacc[(3 * 128 + rr) * 17 + g * 4 + 1];
  s.z = pacc[(0 * 128 + rr) * 17 + g * 4 + 2] + pacc[(1 * 128 + rr) * 17 + g * 4 + 2] +
        pacc[(2 * 128 + rr) * 17 + g * 4 + 2] + pacc[(3 * 128 + rr) * 17 + g * 4 + 2];
  s.w = pacc[(0 * 128 + rr) * 17 + g * 4 + 3] + pacc[(1 * 128 + rr) * 17 + g * 4 + 3] +
        pacc[(2 * 128 + rr) * 17 + g * 4 + 3] + pacc[(3 * 128 + rr) * 17 + g * 4 + 3];
  int orow = r0 + rr;
  if (orow < N_NODES) ((float4*)(h + (size_t)orow * HID))[g] = s;

  float4 av = ((const float4*)atts)[g];
  float4 dv = ((const float4*)attd)[g];
  float pas = s.x * av.x + s.y * av.y + s.z * av.z + s.w * av.w;
  float pad = s.x * dv.x + s.y * dv.y + s.z * dv.z + s.w * dv.w;
  pas += __shfl_xor(pas, 1); pas += __shfl_xor(pas, 2);
  pad += __shfl_xor(pad, 1); pad += __shfl_xor(pad, 2);
  if (g == 0 && orow < N_NODES) { as_[orow] = pas; ad_[orow] = pad; }
}

// ---------- phase 2a: per-bucket exclusive scan over groups ----------
__global__ __launch_bounds__(G_GROUPS) void k_colscan(int* __restrict__ H,
                                                      int* __restrict__ tot) {
  __shared__ int s[G_GROUPS];
  int b = blockIdx.x, t = threadIdx.x;
  int v = H[(size_t)t * NBKT + b];
  s[t] = v;
  __syncthreads();
  for (int off = 1; off < G_GROUPS; off <<= 1) {
    int a = (t >= off) ? s[t - off] : 0;
    __syncthreads();
    s[t] += a;
    __syncthreads();
  }
  H[(size_t)t * NBKT + b] = s[t] - v;     // exclusive prefix within bucket
  if (t == G_GROUPS - 1) tot[b] = s[t];   // bucket total
}

// ---------- phase 2b: scan bucket totals ----------
__global__ __launch_bounds__(256) void k_bscan(const int* __restrict__ tot,
                                               int* __restrict__ bbase,
                                               int* __restrict__ cbase,
                                               int* __restrict__ offs) {
  __shared__ int s1[256], s2[256];
  int t = threadIdx.x;
  int c[4], vn[4];
  int sum1 = 0, sum2 = 0;
#pragma unroll
  for (int j = 0; j < 4; ++j) {
    int idx = t * 4 + j;
    int cc = 0, vv = 0;
    if (idx < NBKT) {
      cc = tot[idx];
      int lo = idx << BSH;
      vv = min(128, N_NODES - lo);
    }
    c[j] = cc; vn[j] = vv;
    sum1 += cc; sum2 += cc + vv;
  }
  int o1 = sum1, o2 = sum2;
  s1[t] = sum1; s2[t] = sum2;
  __syncthreads();
  for (int off = 1; off < 256; off <<= 1) {
    int a = 0, b = 0;
    if (t >= off) { a = s1[t - off]; b = s2[t - off]; }
    __syncthreads();
    s1[t] += a; s2[t] += b;
    __syncthreads();
  }
  int r1 = s1[t] - o1;
  int r2 = s2[t] - o2;
#pragma unroll
  for (int j = 0; j < 4; ++j) {
    int idx = t * 4 + j;
    if (idx < NBKT) {
      bbase[idx] = r1; cbase[idx] = r2;
      r1 += c[j];
      r2 += c[j] + vn[j];
    }
  }
  if (t == 0) offs[N_NODES] = N_TOT;
}

// ---------- phase 3: rank-scatter (2-edge vectorized; LDS cursors) ----------
__global__ __launch_bounds__(256) void k_scatter(const int* __restrict__ ei,
                                                 const int* __restrict__ H,
                                                 const int* __restrict__ bbase,
                                                 int* __restrict__ binned) {
  __shared__ int cur[NBKT];
  __shared__ int sflag;
  int g = blockIdx.x, t = threadIdx.x;
  const int* Hrow = H + (size_t)g * NBKT;
  for (int i = t; i < NBKT; i += 256) cur[i] = bbase[i] + Hrow[i];
  int fl = detect_fl(ei, t, &sflag);   // barrier covers cur init
  int e0 = g * EPG, e1 = e0 + EPG;     // e0, EPG even -> pair alignment holds
  if (fl) {
    for (int e = e0 + t * 2; e < e1; e += 512) {
      int4 sv = *(const int4*)(ei + 2 * (size_t)e);
      int4 dv = *(const int4*)(ei + 2 * ((size_t)N_EDGES + e));
      int s0 = min(max(sv.x, 0), N_NODES - 1);
      int d0 = min(max(dv.x, 0), N_NODES - 1);
      int s1 = min(max(sv.z, 0), N_NODES - 1);
      int d1 = min(max(dv.z, 0), N_NODES - 1);
      int p0 = atomicAdd(&cur[d0 >> BSH], 1);
      binned[min(max(p0, 0), N_EDGES - 1)] = ((d0 & 127) << 17) | s0;
      int p1 = atomicAdd(&cur[d1 >> BSH], 1);
      binned[min(max(p1, 0), N_EDGES - 1)] = ((d1 & 127) << 17) | s1;
    }
  } else {
    for (int e = e0 + t * 2; e < e1; e += 512) {
      int2 sv = *(const int2*)(ei + e);
      int2 dv = *(const int2*)(ei + (size_t)N_EDGES + e);
      int s0 = min(max(sv.x, 0), N_NODES - 1);
      int d0 = min(max(dv.x, 0), N_NODES - 1);
      int s1 = min(max(sv.y, 0), N_NODES - 1);
      int d1 = min(max(dv.y, 0), N_NODES - 1);
      int p0 = atomicAdd(&cur[d0 >> BSH], 1);
      binned[min(max(p0, 0), N_EDGES - 1)] = ((d0 & 127) << 17) | s0;
      int p1 = atomicAdd(&cur[d1 >> BSH], 1);
      binned[min(max(p1, 0), N_EDGES - 1)] = ((d1 & 127) << 17) | s1;
    }
  }
}

// ---------- per-bucket counting sort in LDS -> CSR offs + srcS ----------
__global__ __launch_bounds__(256) void k_bucket(const int* __restrict__ tot,
                                                const int* __restrict__ bbase,
                                                const int* __restrict__ cbase,
                                                const int* __restrict__ binned,
                                                int* __restrict__ offs,
                                                int* __restrict__ srcS) {
  __shared__ int cnt[128], cur[128], sc[128];
  __shared__ int hdr[3];
  int b = blockIdx.x, t = threadIdx.x;
  if (t == 0) {
    hdr[0] = min(max(tot[b], 0), N_EDGES);
    hdr[1] = min(max(bbase[b], 0), N_EDGES - 1);
    hdr[2] = min(max(cbase[b], 0), N_TOT - 1);
  }
  if (t < 128) cnt[t] = 0;
  __syncthreads();
  int nb = hdr[0], base = hdr[1], cb = hdr[2];

  for (int i = t; i < nb; i += 256) {
    int pk = binned[min(base + i, N_EDGES - 1)];
    atomicAdd(&cnt[(pk >> 17) & 127], 1);
  }
  __syncthreads();

  int node = (b << BSH) + t;
  int myv = 0;
  if (t < 128) myv = (node < N_NODES) ? cnt[t] + 1 : 0;  // +1 self loop
  if (t < 128) sc[t] = myv;
  __syncthreads();
  for (int off = 1; off < 128; off <<= 1) {
    int v = 0;
    if (t < 128 && t >= off) v = sc[t - off];
    __syncthreads();
    if (t < 128) sc[t] += v;
    __syncthreads();
  }
  if (t < 128 && node < N_NODES) {
    int lofs = sc[t] - myv;
    int o = min(cb + lofs, N_TOT - 1);
    offs[node] = o;
    srcS[o] = node;                  // self-loop occupies slot 0
    cur[t] = lofs + 1;
  }
  __syncthreads();

  for (int i = t; i < nb; i += 256) {
    int pk = binned[min(base + i, N_EDGES - 1)];
    int p = atomicAdd(&cur[(pk >> 17) & 127], 1);
    srcS[min(cb + p, N_TOT - 1)] = pk & SRC_MASK;
  }
}

// ---------- fused aggregate: single-sweep softmax+gather, float4 lanes ----
template <bool LAYER1>
__global__ __launch_bounds__(256) void k_agg(const int* __restrict__ offs,
                                             const int* __restrict__ srcS,
                                             const float* __restrict__ as_,
                                             const float* __restrict__ ad_,
                                             const float* __restrict__ h,
                                             const float* __restrict__ b1,
                                             const float* __restrict__ ws2,
                                             const float* __restrict__ wd2,
                                             const float* __restrict__ W2,
                                             const float* __restrict__ b2,
                                             float* __restrict__ outv,
                                             float* __restrict__ as2,
                                             float* __restrict__ ad2) {
  int node = blockIdx.x * 4 + (threadIdx.x >> 6);
  if (node >= N_NODES) return;
  int lane = threadIdx.x & 63;
  int esub = lane >> 2;     // 16 edge slots per step
  int f4 = lane & 3;        // feature quad
  int beg = offs[node];
  int end = offs[node + 1];
  beg = min(max(beg, 0), N_TOT);
  end = min(max(end, beg), N_TOT);
  float ad = ad_[node];

  float s_lane = 0.f;
  float4 acc = make_float4(0.f, 0.f, 0.f, 0.f);
  for (int i0 = beg; i0 < end; i0 += 64) {
    int nb = min(64, end - i0);
    int sn = 0;
    float p = 0.f;
    if (lane < nb) {
      sn = min(max(srcS[i0 + lane], 0), N_NODES - 1);
      float e = as_[sn] + ad;
      e = e > 0.f ? e : NEG_SLOPE * e;
      p = __expf(e);           // no max-shift: |e| <= ~12, exp safe in fp32
    }
    s_lane += p;
    int steps = (nb + 15) >> 4;
    for (int t = 0; t < steps; ++t) {
      int j = esub + 16 * t;
      int jj = min(j, nb - 1);           // clamp so source lane is valid
      float pj = __shfl(p, jj);          // full wave active
      int snj = __shfl(sn, jj);
      if (j < nb) {
        float4 v = ((const float4*)(h + (size_t)snj * HID))[f4];
        acc.x += pj * v.x;
        acc.y += pj * v.y;
        acc.z += pj * v.z;
        acc.w += pj * v.w;
      }
    }
  }
#pragma unroll
  for (int off = 1; off < 64; off <<= 1) s_lane += __shfl_xor(s_lane, off);
#pragma unroll
  for (int off = 4; off < 64; off <<= 1) {
    acc.x += __shfl_xor(acc.x, off);
    acc.y += __shfl_xor(acc.y, off);
    acc.z += __shfl_xor(acc.z, off);
    acc.w += __shfl_xor(acc.w, off);
  }
  float inv_s = 1.f / s_lane;

  if (LAYER1) {
    float4 bv = ((const float4*)b1)[f4];
    float4 val;
    val.x = fmaxf(acc.x * inv_s + bv.x, 0.f);
    val.y = fmaxf(acc.y * inv_s + bv.y, 0.f);
    val.z = fmaxf(acc.z * inv_s + bv.z, 0.f);
    val.w = fmaxf(acc.w * inv_s + bv.w, 0.f);
    if (lane < 4) ((float4*)(outv + (size_t)node * HID))[lane] = val;
    float4 w_s = ((const float4*)ws2)[f4];
    float4 w_d = ((const float4*)wd2)[f4];
    float rs = val.x * w_s.x + val.y * w_s.y + val.z * w_s.z + val.w * w_s.w;
    float rd = val.x * w_d.x + val.y * w_d.y + val.z * w_d.z + val.w * w_d.w;
    rs += __shfl_xor(rs, 1); rs += __shfl_xor(rs, 2);
    rd += __shfl_xor(rd, 1); rd += __shfl_xor(rd, 2);
    if (lane == 0) { as2[node] = rs; ad2[node] = rd; }
  } else {
    // fused k_out: broadcast 16-dim aggregate (full-wave shuffles, sources
    // (lane&~3)|j always valid), per-lane logit, 32-lane log_softmax.
    float hv[HID];
#pragma unroll
    for (int j = 0; j < 4; ++j) {
      int srcl = (lane & ~3) | j;
      hv[4 * j + 0] = __shfl(acc.x, srcl) * inv_s;
      hv[4 * j + 1] = __shfl(acc.y, srcl) * inv_s;
      hv[4 * j + 2] = __shfl(acc.z, srcl) * inv_s;
      hv[4 * j + 3] = __shfl(acc.w, srcl) * inv_s;
    }
    int c = lane & 31;
    float logit = b2[c];
#pragma unroll
    for (int k = 0; k < HID; ++k) logit += hv[k] * W2[k * NCLS + c];
    float mx = logit;
#pragma unroll
    for (int off = 1; off < 32; off <<= 1) mx = fmaxf(mx, __shfl_xor(mx, off));
    float ex = __expf(logit - mx);
    float se = ex;
#pragma unroll
    for (int off = 1; off < 32; off <<= 1) se += __shfl_xor(se, off);
    if (lane < 32) outv[(size_t)node * NCLS + c] = logit - mx - __logf(se);
  }
}

extern "C" void kernel_launch(void* const* d_in, const int* in_sizes, int n_in,
                              void* d_out, int out_size, void* d_ws, size_t ws_size,
                              hipStream_t stream) {
  const float* x    = (const float*)d_in[0];
  const int*   ei   = (const int*)d_in[1];
  const float* W1   = (const float*)d_in[2];
  const float* as1w = (const float*)d_in[3];
  const float* ad1w = (const float*)d_in[4];
  const float* b1   = (const float*)d_in[5];
  const float* W2   = (const float*)d_in[6];
  const float* as2w = (const float*)d_in[7];
  const float* ad2w = (const float*)d_in[8];
  const float* b2   = (const float*)d_in[9];
  float* out = (float*)d_out;

  char* w = (char*)d_ws;
  size_t off = 0;
  auto alloc = [&](size_t bytes) -> char* {
    char* p = w + off;
    off += (bytes + 511) & ~(size_t)511;
    return p;
  };
  int*   tot   = (int*)alloc((size_t)NBKT * 4);
  int*   bbase = (int*)alloc((size_t)NBKT * 4);
  int*   cbase = (int*)alloc((size_t)NBKT * 4);
  int*   offs  = (int*)alloc((size_t)(N_NODES + 1) * 4);
  int*   srcS  = (int*)alloc((size_t)N_TOT * 4);
  float* ws2   = (float*)alloc((size_t)HID * 4);
  float* wd2   = (float*)alloc((size_t)HID * 4);
  int*   H     = (int*)alloc((size_t)G_GROUPS * NBKT * 4);  // 1.6 MB
  float* h1    = (float*)alloc((size_t)N_NODES * HID * 4);
  float* as1   = (float*)alloc((size_t)N_NODES * 4);
  float* ad1   = (float*)alloc((size_t)N_NODES * 4);

  // union: binned (12.8MB, dead after k_bucket) vs {hr, as2, ad2}
  // (written by k_agg<true>, which runs after k_bucket — stream-ordered).
  size_t region_begin = off;
  int* binned = (int*)alloc((size_t)N_EDGES * 4);
  off = region_begin;
  float* hr   = (float*)alloc((size_t)N_NODES * HID * 4);
  float* as2  = (float*)alloc((size_t)N_NODES * 4);
  float* ad2  = (float*)alloc((size_t)N_NODES * 4);

  k_g1h<<<NGEMM + G_GROUPS + 1, 512, 0, stream>>>(x, W1, as1w, ad1w, ei, H,
                                                  W2, as2w, ad2w, ws2, wd2,
                                                  h1, as1, ad1);
  k_colscan<<<NBKT, G_GROUPS, 0, stream>>>(H, tot);
  k_bscan<<<1, 256, 0, stream>>>(tot, bbase, cbase, offs);
  k_scatter<<<G_GROUPS, 256, 0, stream>>>(ei, H, bbase, binned);
  k_bucket<<<NBKT, 256, 0, stream>>>(tot, bbase, cbase, binned, offs, srcS);
  k_agg<true><<<(N_NODES + 3) / 4, 256, 0, stream>>>(offs, srcS, as1, ad1, h1,
                                                     b1, ws2, wd2, nullptr, nullptr,
                                                     hr, as2, ad2);
  k_agg<false><<<(N_NODES + 3) / 4, 256, 0, stream>>>(offs, srcS, as2, ad2, hr,
                                                      nullptr, nullptr, nullptr,
                                                      W2, b2, out, nullptr, nullptr);
}

// Round 14
// 244.241 us; speedup vs baseline: 1.4903x; 1.0534x over previous
//
#include <hip/hip_runtime.h>
#include <hip/hip_fp16.h>
#include <math.h>

#define N_NODES 100000
#define N_EDGES 3200000
#define N_TOT   (N_EDGES + N_NODES)
#define F_IN    512
#define HID     16
#define NCLS    32
#define NEG_SLOPE 0.2f

#define BSH   7                       // bucket shift: 128 nodes per bucket
#define NBKT  ((N_NODES + 127) / 128) // 782
#define SRC_MASK 0x1FFFF              // 17 bits, N_NODES < 131072

#define G_GROUPS 512
#define EPG (N_EDGES / G_GROUPS)      // 6250 exact (even)
#define NGEMM ((N_NODES + 127) / 128) // 782 gemm blocks

typedef __attribute__((ext_vector_type(4))) _Float16 h4_t;  // 8B fp16 quad

// ---------- in-block edge-dtype detection (int64 vs int32) ----------
__device__ __forceinline__ int detect_fl(const int* __restrict__ ei,
                                         int t, int* sflag) {
  if (t < 64) {
    int v = ei[2 * t + 1];
    unsigned long long m = __ballot(v != 0);
    if (t == 0) *sflag = (m == 0ull) ? 1 : 0;  // 1 => int64 layout
  }
  __syncthreads();
  return *sflag;
}

// ---------- hybrid: gemm1 (782 blocks) + hist (512) + prep (1) ----------
__global__ __launch_bounds__(512) void k_g1h(const float* __restrict__ x,
                                             const float* __restrict__ W,
                                             const float* __restrict__ atts,
                                             const float* __restrict__ attd,
                                             const int* __restrict__ ei,
                                             int* __restrict__ H,
                                             const float* __restrict__ W2,
                                             const float* __restrict__ as2w,
                                             const float* __restrict__ ad2w,
                                             float* __restrict__ ws2,
                                             float* __restrict__ wd2,
                                             _Float16* __restrict__ h,
                                             float* __restrict__ as_,
                                             float* __restrict__ ad_) {
  __shared__ float smem[2 * 128 * 36];   // 36.9KB, reinterpreted per role
  int bid = blockIdx.x;
  int t = threadIdx.x;

  if (bid >= NGEMM) {
    if (bid < NGEMM + G_GROUPS) {
      // ---- hist role ----
      int* hh = (int*)smem;
      int* sflag = hh + NBKT;
      for (int i = t; i < NBKT; i += 512) hh[i] = 0;
      int fl = detect_fl(ei, t, sflag);   // barrier covers hh init
      int g = bid - NGEMM;
      int e0 = g * EPG, e1 = e0 + EPG;
      for (int e = e0 + t; e < e1; e += 512) {
        int d = fl ? ei[2 * (N_EDGES + e)] : ei[N_EDGES + e];
        d = min(max(d, 0), N_NODES - 1);
        atomicAdd(&hh[d >> BSH], 1);
      }
      __syncthreads();
      int* Hrow = H + (size_t)g * NBKT;
      for (int i = t; i < NBKT; i += 512) Hrow[i] = hh[i];
    } else {
      // ---- prep role ----
      if (t < HID) {
        float s = 0.f, d = 0.f;
        for (int c = 0; c < NCLS; ++c) {
          float wv = W2[t * NCLS + c];
          s += wv * as2w[c];
          d += wv * ad2w[c];
        }
        ws2[t] = s;
        wd2[t] = d;
      }
    }
    return;
  }

  // ---- gemm role: async-STAGE split double-buffer, scalar-path W ----
  float (*xs)[128][36] = (float (*)[128][36])smem;
  float* pacc = smem;                  // reused as [4][128][17] after compute
  int wid = t >> 6;
  int lane = t & 63;
  int rhalf = wid & 1;
  int kq = __builtin_amdgcn_readfirstlane(wid >> 1);  // SGPR -> s_load path
  int row = rhalf * 64 + lane;
  int r0 = bid * 128;

  int sr = t >> 3;
  int sk4 = t & 7;
  int sr2 = (t + 512) >> 3;
  int sk42 = (t + 512) & 7;
  const float* xp1 = x + (size_t)min(r0 + sr, N_NODES - 1) * F_IN + sk4 * 4;
  const float* xp2 = x + (size_t)min(r0 + sr2, N_NODES - 1) * F_IN + sk42 * 4;

  float acc[HID];
#pragma unroll
  for (int f = 0; f < HID; ++f) acc[f] = 0.f;

  float4 a0, a1, b0, b1;
  a0 = *(const float4*)(xp1 + 0 * 32);
  a1 = *(const float4*)(xp2 + 0 * 32);
  *(float4*)(&xs[0][sr][sk4 * 4]) = a0;
  *(float4*)(&xs[0][sr2][sk42 * 4]) = a1;
  a0 = *(const float4*)(xp1 + 1 * 32);
  a1 = *(const float4*)(xp2 + 1 * 32);
  __syncthreads();

#pragma unroll
  for (int cc = 0; cc < 8; ++cc) {
    const int c = 2 * cc;
    if (cc < 7) {
      b0 = *(const float4*)(xp1 + (c + 2) * 32);
      b1 = *(const float4*)(xp2 + (c + 2) * 32);
    }
    {
      const float* Wc = W + (c * 32 + kq * 8) * HID;
      float4 xa = *(const float4*)(&xs[0][row][kq * 8 + 0]);
      float4 xb = *(const float4*)(&xs[0][row][kq * 8 + 4]);
#pragma unroll
      for (int f = 0; f < HID; ++f)
        acc[f] += xa.x * Wc[0 * HID + f] + xa.y * Wc[1 * HID + f] +
                  xa.z * Wc[2 * HID + f] + xa.w * Wc[3 * HID + f];
#pragma unroll
      for (int f = 0; f < HID; ++f)
        acc[f] += xb.x * Wc[4 * HID + f] + xb.y * Wc[5 * HID + f] +
                  xb.z * Wc[6 * HID + f] + xb.w * Wc[7 * HID + f];
    }
    *(float4*)(&xs[1][sr][sk4 * 4]) = a0;
    *(float4*)(&xs[1][sr2][sk42 * 4]) = a1;
    __syncthreads();
    if (cc < 7) {
      a0 = *(const float4*)(xp1 + (c + 3) * 32);
      a1 = *(const float4*)(xp2 + (c + 3) * 32);
    }
    {
      const float* Wc = W + ((c + 1) * 32 + kq * 8) * HID;
      float4 xa = *(const float4*)(&xs[1][row][kq * 8 + 0]);
      float4 xb = *(const float4*)(&xs[1][row][kq * 8 + 4]);
#pragma unroll
      for (int f = 0; f < HID; ++f)
        acc[f] += xa.x * Wc[0 * HID + f] + xa.y * Wc[1 * HID + f] +
                  xa.z * Wc[2 * HID + f] + xa.w * Wc[3 * HID + f];
#pragma unroll
      for (int f = 0; f < HID; ++f)
        acc[f] += xb.x * Wc[4 * HID + f] + xb.y * Wc[5 * HID + f] +
                  xb.z * Wc[6 * HID + f] + xb.w * Wc[7 * HID + f];
    }
    if (cc < 7) {
      *(float4*)(&xs[0][sr][sk4 * 4]) = b0;
      *(float4*)(&xs[0][sr2][sk42 * 4]) = b1;
    }
    __syncthreads();
  }

#pragma unroll
  for (int f = 0; f < HID; ++f) pacc[(kq * 128 + row) * 17 + f] = acc[f];
  __syncthreads();

  int rr = t >> 2, g = t & 3;
  float4 s;
  s.x = pacc[(0 * 128 + rr) * 17 + g * 4 + 0] + pacc[(1 * 128 + rr) * 17 + g * 4 + 0] +
        pacc[(2 * 128 + rr) * 17 + g * 4 + 0] + pacc[(3 * 128 + rr) * 17 + g * 4 + 0];
  s.y = pacc[(0 * 128 + rr) * 17 + g * 4 + 1] + pacc[(1 * 128 + rr) * 17 + g * 4 + 1] +
        pacc[(2 * 128 + rr) * 17 + g * 4 + 1] + pacc[(3 * 128 + rr) * 17 + g * 4 + 1];
  s.z = pacc[(0 * 128 + rr) * 17 + g * 4 + 2] + pacc[(1 * 128 + rr) * 17 + g * 4 + 2] +
        pacc[(2 * 128 + rr) * 17 + g * 4 + 2] + pacc[(3 * 128 + rr) * 17 + g * 4 + 2];
  s.w = pacc[(0 * 128 + rr) * 17 + g * 4 + 3] + pacc[(1 * 128 + rr) * 17 + g * 4 + 3] +
        pacc[(2 * 128 + rr) * 17 + g * 4 + 3] + pacc[(3 * 128 + rr) * 17 + g * 4 + 3];
  int orow = r0 + rr;
  if (orow < N_NODES) {
    h4_t hv;
    hv.x = (_Float16)s.x; hv.y = (_Float16)s.y;
    hv.z = (_Float16)s.z; hv.w = (_Float16)s.w;
    *(h4_t*)(h + (size_t)orow * HID + g * 4) = hv;   // fp16 row: 32B, L2-fit
  }

  float4 av = ((const float4*)atts)[g];
  float4 dv = ((const float4*)attd)[g];
  float pas = s.x * av.x + s.y * av.y + s.z * av.z + s.w * av.w;
  float pad = s.x * dv.x + s.y * dv.y + s.z * dv.z + s.w * dv.w;
  pas += __shfl_xor(pas, 1); pas += __shfl_xor(pas, 2);
  pad += __shfl_xor(pad, 1); pad += __shfl_xor(pad, 2);
  if (g == 0 && orow < N_NODES) { as_[orow] = pas; ad_[orow] = pad; }
}

// ---------- phase 2a: per-bucket exclusive scan over groups ----------
__global__ __launch_bounds__(G_GROUPS) void k_colscan(int* __restrict__ H,
                                                      int* __restrict__ tot) {
  __shared__ int s[G_GROUPS];
  int b = blockIdx.x, t = threadIdx.x;
  int v = H[(size_t)t * NBKT + b];
  s[t] = v;
  __syncthreads();
  for (int off = 1; off < G_GROUPS; off <<= 1) {
    int a = (t >= off) ? s[t - off] : 0;
    __syncthreads();
    s[t] += a;
    __syncthreads();
  }
  H[(size_t)t * NBKT + b] = s[t] - v;     // exclusive prefix within bucket
  if (t == G_GROUPS - 1) tot[b] = s[t];   // bucket total
}

// ---------- phase 2b: scan bucket totals ----------
__global__ __launch_bounds__(256) void k_bscan(const int* __restrict__ tot,
                                               int* __restrict__ bbase,
                                               int* __restrict__ cbase,
                                               int* __restrict__ offs) {
  __shared__ int s1[256], s2[256];
  int t = threadIdx.x;
  int c[4], vn[4];
  int sum1 = 0, sum2 = 0;
#pragma unroll
  for (int j = 0; j < 4; ++j) {
    int idx = t * 4 + j;
    int cc = 0, vv = 0;
    if (idx < NBKT) {
      cc = tot[idx];
      int lo = idx << BSH;
      vv = min(128, N_NODES - lo);
    }
    c[j] = cc; vn[j] = vv;
    sum1 += cc; sum2 += cc + vv;
  }
  int o1 = sum1, o2 = sum2;
  s1[t] = sum1; s2[t] = sum2;
  __syncthreads();
  for (int off = 1; off < 256; off <<= 1) {
    int a = 0, b = 0;
    if (t >= off) { a = s1[t - off]; b = s2[t - off]; }
    __syncthreads();
    s1[t] += a; s2[t] += b;
    __syncthreads();
  }
  int r1 = s1[t] - o1;
  int r2 = s2[t] - o2;
#pragma unroll
  for (int j = 0; j < 4; ++j) {
    int idx = t * 4 + j;
    if (idx < NBKT) {
      bbase[idx] = r1; cbase[idx] = r2;
      r1 += c[j];
      r2 += c[j] + vn[j];
    }
  }
  if (t == 0) offs[N_NODES] = N_TOT;
}

// ---------- phase 3: rank-scatter (2-edge vectorized; LDS cursors) ----------
__global__ __launch_bounds__(256) void k_scatter(const int* __restrict__ ei,
                                                 const int* __restrict__ H,
                                                 const int* __restrict__ bbase,
                                                 int* __restrict__ binned) {
  __shared__ int cur[NBKT];
  __shared__ int sflag;
  int g = blockIdx.x, t = threadIdx.x;
  const int* Hrow = H + (size_t)g * NBKT;
  for (int i = t; i < NBKT; i += 256) cur[i] = bbase[i] + Hrow[i];
  int fl = detect_fl(ei, t, &sflag);   // barrier covers cur init
  int e0 = g * EPG, e1 = e0 + EPG;
  if (fl) {
    for (int e = e0 + t * 2; e < e1; e += 512) {
      int4 sv = *(const int4*)(ei + 2 * (size_t)e);
      int4 dv = *(const int4*)(ei + 2 * ((size_t)N_EDGES + e));
      int s0 = min(max(sv.x, 0), N_NODES - 1);
      int d0 = min(max(dv.x, 0), N_NODES - 1);
      int s1 = min(max(sv.z, 0), N_NODES - 1);
      int d1 = min(max(dv.z, 0), N_NODES - 1);
      int p0 = atomicAdd(&cur[d0 >> BSH], 1);
      binned[min(max(p0, 0), N_EDGES - 1)] = ((d0 & 127) << 17) | s0;
      int p1 = atomicAdd(&cur[d1 >> BSH], 1);
      binned[min(max(p1, 0), N_EDGES - 1)] = ((d1 & 127) << 17) | s1;
    }
  } else {
    for (int e = e0 + t * 2; e < e1; e += 512) {
      int2 sv = *(const int2*)(ei + e);
      int2 dv = *(const int2*)(ei + (size_t)N_EDGES + e);
      int s0 = min(max(sv.x, 0), N_NODES - 1);
      int d0 = min(max(dv.x, 0), N_NODES - 1);
      int s1 = min(max(sv.y, 0), N_NODES - 1);
      int d1 = min(max(dv.y, 0), N_NODES - 1);
      int p0 = atomicAdd(&cur[d0 >> BSH], 1);
      binned[min(max(p0, 0), N_EDGES - 1)] = ((d0 & 127) << 17) | s0;
      int p1 = atomicAdd(&cur[d1 >> BSH], 1);
      binned[min(max(p1, 0), N_EDGES - 1)] = ((d1 & 127) << 17) | s1;
    }
  }
}

// ---------- per-bucket counting sort in LDS -> CSR offs + srcS ----------
__global__ __launch_bounds__(256) void k_bucket(const int* __restrict__ tot,
                                                const int* __restrict__ bbase,
                                                const int* __restrict__ cbase,
                                                const int* __restrict__ binned,
                                                int* __restrict__ offs,
                                                int* __restrict__ srcS) {
  __shared__ int cnt[128], cur[128], sc[128];
  __shared__ int hdr[3];
  int b = blockIdx.x, t = threadIdx.x;
  if (t == 0) {
    hdr[0] = min(max(tot[b], 0), N_EDGES);
    hdr[1] = min(max(bbase[b], 0), N_EDGES - 1);
    hdr[2] = min(max(cbase[b], 0), N_TOT - 1);
  }
  if (t < 128) cnt[t] = 0;
  __syncthreads();
  int nb = hdr[0], base = hdr[1], cb = hdr[2];

  for (int i = t; i < nb; i += 256) {
    int pk = binned[min(base + i, N_EDGES - 1)];
    atomicAdd(&cnt[(pk >> 17) & 127], 1);
  }
  __syncthreads();

  int node = (b << BSH) + t;
  int myv = 0;
  if (t < 128) myv = (node < N_NODES) ? cnt[t] + 1 : 0;  // +1 self loop
  if (t < 128) sc[t] = myv;
  __syncthreads();
  for (int off = 1; off < 128; off <<= 1) {
    int v = 0;
    if (t < 128 && t >= off) v = sc[t - off];
    __syncthreads();
    if (t < 128) sc[t] += v;
    __syncthreads();
  }
  if (t < 128 && node < N_NODES) {
    int lofs = sc[t] - myv;
    int o = min(cb + lofs, N_TOT - 1);
    offs[node] = o;
    srcS[o] = node;                  // self-loop occupies slot 0
    cur[t] = lofs + 1;
  }
  __syncthreads();

  for (int i = t; i < nb; i += 256) {
    int pk = binned[min(base + i, N_EDGES - 1)];
    int p = atomicAdd(&cur[(pk >> 17) & 127], 1);
    srcS[min(cb + p, N_TOT - 1)] = pk & SRC_MASK;
  }
}

// ---------- fused aggregate: single-sweep softmax+gather, fp16 h rows ----
// Wave per node. h rows are 32B fp16 (3.2MB total -> XCD-L2 resident).
// All shuffles full-wave (clamped source, predicated use).
template <bool LAYER1>
__global__ __launch_bounds__(256) void k_agg(const int* __restrict__ offs,
                                             const int* __restrict__ srcS,
                                             const float* __restrict__ as_,
                                             const float* __restrict__ ad_,
                                             const _Float16* __restrict__ h,
                                             const float* __restrict__ b1,
                                             const float* __restrict__ ws2,
                                             const float* __restrict__ wd2,
                                             const float* __restrict__ W2,
                                             const float* __restrict__ b2,
                                             _Float16* __restrict__ outh,
                                             float* __restrict__ outf,
                                             float* __restrict__ as2,
                                             float* __restrict__ ad2) {
  int node = blockIdx.x * 4 + (threadIdx.x >> 6);
  if (node >= N_NODES) return;
  int lane = threadIdx.x & 63;
  int esub = lane >> 2;     // 16 edge slots per step
  int f4 = lane & 3;        // feature quad
  int beg = offs[node];
  int end = offs[node + 1];
  beg = min(max(beg, 0), N_TOT);
  end = min(max(end, beg), N_TOT);
  float ad = ad_[node];

  float s_lane = 0.f;
  float4 acc = make_float4(0.f, 0.f, 0.f, 0.f);
  for (int i0 = beg; i0 < end; i0 += 64) {
    int nb = min(64, end - i0);
    int sn = 0;
    float p = 0.f;
    if (lane < nb) {
      sn = min(max(srcS[i0 + lane], 0), N_NODES - 1);
      float e = as_[sn] + ad;
      e = e > 0.f ? e : NEG_SLOPE * e;
      p = __expf(e);           // no max-shift: |e| <= ~12, exp safe in fp32
    }
    s_lane += p;
    int steps = (nb + 15) >> 4;
    for (int t = 0; t < steps; ++t) {
      int j = esub + 16 * t;
      int jj = min(j, nb - 1);           // clamp so source lane is valid
      float pj = __shfl(p, jj);          // full wave active
      int snj = __shfl(sn, jj);
      if (j < nb) {
        h4_t v = *(const h4_t*)(h + (size_t)snj * HID + f4 * 4);
        acc.x += pj * (float)v.x;
        acc.y += pj * (float)v.y;
        acc.z += pj * (float)v.z;
        acc.w += pj * (float)v.w;
      }
    }
  }
#pragma unroll
  for (int off = 1; off < 64; off <<= 1) s_lane += __shfl_xor(s_lane, off);
#pragma unroll
  for (int off = 4; off < 64; off <<= 1) {
    acc.x += __shfl_xor(acc.x, off);
    acc.y += __shfl_xor(acc.y, off);
    acc.z += __shfl_xor(acc.z, off);
    acc.w += __shfl_xor(acc.w, off);
  }
  float inv_s = 1.f / s_lane;

  if (LAYER1) {
    float4 bv = ((const float4*)b1)[f4];
    float4 val;
    val.x = fmaxf(acc.x * inv_s + bv.x, 0.f);
    val.y = fmaxf(acc.y * inv_s + bv.y, 0.f);
    val.z = fmaxf(acc.z * inv_s + bv.z, 0.f);
    val.w = fmaxf(acc.w * inv_s + bv.w, 0.f);
    if (lane < 4) {
      h4_t hv;
      hv.x = (_Float16)val.x; hv.y = (_Float16)val.y;
      hv.z = (_Float16)val.z; hv.w = (_Float16)val.w;
      *(h4_t*)(outh + (size_t)node * HID + lane * 4) = hv;
    }
    // fused layer-2 scores from fp32 values (no extra rounding)
    float4 w_s = ((const float4*)ws2)[f4];
    float4 w_d = ((const float4*)wd2)[f4];
    float rs = val.x * w_s.x + val.y * w_s.y + val.z * w_s.z + val.w * w_s.w;
    float rd = val.x * w_d.x + val.y * w_d.y + val.z * w_d.z + val.w * w_d.w;
    rs += __shfl_xor(rs, 1); rs += __shfl_xor(rs, 2);
    rd += __shfl_xor(rd, 1); rd += __shfl_xor(rd, 2);
    if (lane == 0) { as2[node] = rs; ad2[node] = rd; }
  } else {
    // fused k_out: broadcast 16-dim aggregate (full-wave shuffles, sources
    // (lane&~3)|j always valid), per-lane logit, 32-lane log_softmax.
    float hv[HID];
#pragma unroll
    for (int j = 0; j < 4; ++j) {
      int srcl = (lane & ~3) | j;
      hv[4 * j + 0] = __shfl(acc.x, srcl) * inv_s;
      hv[4 * j + 1] = __shfl(acc.y, srcl) * inv_s;
      hv[4 * j + 2] = __shfl(acc.z, srcl) * inv_s;
      hv[4 * j + 3] = __shfl(acc.w, srcl) * inv_s;
    }
    int c = lane & 31;
    float logit = b2[c];
#pragma unroll
    for (int k = 0; k < HID; ++k) logit += hv[k] * W2[k * NCLS + c];
    float mx = logit;
#pragma unroll
    for (int off = 1; off < 32; off <<= 1) mx = fmaxf(mx, __shfl_xor(mx, off));
    float ex = __expf(logit - mx);
    float se = ex;
#pragma unroll
    for (int off = 1; off < 32; off <<= 1) se += __shfl_xor(se, off);
    if (lane < 32) outf[(size_t)node * NCLS + c] = logit - mx - __logf(se);
  }
}

extern "C" void kernel_launch(void* const* d_in, const int* in_sizes, int n_in,
                              void* d_out, int out_size, void* d_ws, size_t ws_size,
                              hipStream_t stream) {
  const float* x    = (const float*)d_in[0];
  const int*   ei   = (const int*)d_in[1];
  const float* W1   = (const float*)d_in[2];
  const float* as1w = (const float*)d_in[3];
  const float* ad1w = (const float*)d_in[4];
  const float* b1   = (const float*)d_in[5];
  const float* W2   = (const float*)d_in[6];
  const float* as2w = (const float*)d_in[7];
  const float* ad2w = (const float*)d_in[8];
  const float* b2   = (const float*)d_in[9];
  float* out = (float*)d_out;

  char* w = (char*)d_ws;
  size_t off = 0;
  auto alloc = [&](size_t bytes) -> char* {
    char* p = w + off;
    off += (bytes + 511) & ~(size_t)511;
    return p;
  };
  int*      tot   = (int*)alloc((size_t)NBKT * 4);
  int*      bbase = (int*)alloc((size_t)NBKT * 4);
  int*      cbase = (int*)alloc((size_t)NBKT * 4);
  int*      offs  = (int*)alloc((size_t)(N_NODES + 1) * 4);
  int*      srcS  = (int*)alloc((size_t)N_TOT * 4);
  float*    ws2   = (float*)alloc((size_t)HID * 4);
  float*    wd2   = (float*)alloc((size_t)HID * 4);
  int*      H     = (int*)alloc((size_t)G_GROUPS * NBKT * 4);  // 1.6 MB
  _Float16* h1    = (_Float16*)alloc((size_t)N_NODES * HID * 2);  // 3.2 MB fp16
  float*    as1   = (float*)alloc((size_t)N_NODES * 4);
  float*    ad1   = (float*)alloc((size_t)N_NODES * 4);

  // union: binned (12.8MB, dead after k_bucket) vs {hr, as2, ad2}
  // (written by k_agg<true>, which runs after k_bucket — stream-ordered).
  size_t region_begin = off;
  int* binned = (int*)alloc((size_t)N_EDGES * 4);
  off = region_begin;
  _Float16* hr = (_Float16*)alloc((size_t)N_NODES * HID * 2);    // 3.2 MB fp16
  float*    as2 = (float*)alloc((size_t)N_NODES * 4);
  float*    ad2 = (float*)alloc((size_t)N_NODES * 4);

  k_g1h<<<NGEMM + G_GROUPS + 1, 512, 0, stream>>>(x, W1, as1w, ad1w, ei, H,
                                                  W2, as2w, ad2w, ws2, wd2,
                                                  h1, as1, ad1);
  k_colscan<<<NBKT, G_GROUPS, 0, stream>>>(H, tot);
  k_bscan<<<1, 256, 0, stream>>>(tot, bbase, cbase, offs);
  k_scatter<<<G_GROUPS, 256, 0, stream>>>(ei, H, bbase, binned);
  k_bucket<<<NBKT, 256, 0, stream>>>(tot, bbase, cbase, binned, offs, srcS);
  k_agg<true><<<(N_NODES + 3) / 4, 256, 0, stream>>>(offs, srcS, as1, ad1, h1,
                                                     b1, ws2, wd2, nullptr, nullptr,
                                                     hr, nullptr, as2, ad2);
  k_agg<false><<<(N_NODES + 3) / 4, 256, 0, stream>>>(offs, srcS, as2, ad2, hr,
                                                      nullptr, nullptr, nullptr,
                                                      W2, b2, nullptr, out,
                                                      nullptr, nullptr);
}